// Round 2
// baseline (376.436 us; speedup 1.0000x reference)
//
#include <hip/hip_runtime.h>
#include <stdint.h>

// Problem constants (B=8, T=4096, Zc=512, D=256, K=8192)
#define M_TOT 32768
#define ZC 512
#define DD 256
#define KCODES 8192
#define NGRAN 512            // KCODES / 16 codes per granule
#define MARGIN 0.15f         // >2x hard fp16-error bound (validated R2/R3/R4)
#define NBUCKET 256

typedef _Float16 half8   __attribute__((ext_vector_type(8)));
typedef _Float16 half2v  __attribute__((ext_vector_type(2)));
typedef float    float4v __attribute__((ext_vector_type(4)));
typedef float    float16v __attribute__((ext_vector_type(16)));

// Workspace layout (bytes). wt_hi/wt_lo overlap smin: prep_w/gemm1 finish
// before k_dist writes smin (stream-ordered, every launch identical).
#define OFF_H     0ull                  // h fp32: 32 MB
#define OFF_HT    33554432ull           // ht fp16 tiled: 16 MB
#define OFF_CBT   50331648ull           // cbt fp16 tiled: 4 MB
#define OFF_HH    54525952ull           // hh: 128 KB
#define OFF_EE    54657024ull           // ee: 32 KB
#define OFF_LOSSP 54689792ull           // loss buckets: 1 KB
#define OFF_SMIN  54691840ull           // smin_T fp16 [NGRAN][M_TOT]: 32 MB
#define OFF_WTH   OFF_SMIN              // Wt_hi fp16 tiled: 512 KB (overlap)
#define OFF_WTL   (OFF_SMIN + 524288ull) // Wt_lo fp16 tiled: 512 KB (overlap)

// async global->LDS, 16B per lane, LDS dst = wave-uniform base + lane*16
#define ASYNC_CP16(gp, lp)                                                     \
  __builtin_amdgcn_global_load_lds(                                            \
      (const __attribute__((address_space(1))) void*)(gp),                     \
      (__attribute__((address_space(3))) void*)(lp), 16, 0, 0)

// ---------------------------------------------------------------------------
// Prep W: split-fp16 (hi+lo) of W[512][256], stored MFMA-B-tiled:
// off(n,k) = ((n>>5)*64 + (k>>3))*256 + (n&31)*8 + (k&7)
// ---------------------------------------------------------------------------
__global__ __launch_bounds__(256) void k_prep_w(const float* __restrict__ W,
                                                _Float16* __restrict__ wt_hi,
                                                _Float16* __restrict__ wt_lo) {
    const int idx = blockIdx.x * 256 + threadIdx.x;  // 131072
    const int n = idx & 255, k = idx >> 8;
    const float v = W[(size_t)k * DD + n];
    const _Float16 hi = (_Float16)v;
    const _Float16 lo = (_Float16)(v - (float)hi);
    const int off = (((n >> 5) * 64 + (k >> 3)) << 8) + ((n & 31) << 3) + (k & 7);
    wt_hi[off] = hi;
    wt_lo[off] = lo;
}

// ---------------------------------------------------------------------------
// K1: h = x@W + b via split-fp16 MFMA (hi*hi + hi*lo + lo*hi). Verified R4.
// ---------------------------------------------------------------------------
__global__ __launch_bounds__(256) void k_gemm1(const float* __restrict__ x,
                                               const _Float16* __restrict__ wt_hi,
                                               const _Float16* __restrict__ wt_lo,
                                               const float* __restrict__ b,
                                               float* __restrict__ h) {
    __shared__ _Float16 sH[64 * 64];  // tiled [mblk2][kg8][32][8]
    __shared__ _Float16 sL[64 * 64];
    const int tid = threadIdx.x, lane = tid & 63, w = tid >> 6;
    const int wy = w >> 1, wx = w & 1;
    const int m0 = blockIdx.x * 64;

    float16v acc[4];
#pragma unroll
    for (int j = 0; j < 4; ++j) acc[j] = (float16v)(0.0f);

    for (int kb = 0; kb < ZC; kb += 64) {
        __syncthreads();
        {
            const int m = tid & 63;
            const int kp = tid >> 6;  // 0..3
#pragma unroll
            for (int i2 = 0; i2 < 2; ++i2) {
                const int kg = kp * 2 + i2;
                const float* src = x + (size_t)(m0 + m) * ZC + kb + kg * 8;
                float4v v0 = *(const float4v*)src;
                float4v v1 = *(const float4v*)(src + 4);
                half8 hi, lo;
                float vv[8] = {v0.x, v0.y, v0.z, v0.w, v1.x, v1.y, v1.z, v1.w};
#pragma unroll
                for (int j = 0; j < 8; ++j) {
                    hi[j] = (_Float16)vv[j];
                    lo[j] = (_Float16)(vv[j] - (float)hi[j]);
                }
                const int off = (((m >> 5) * 8 + kg) << 8) + ((m & 31) << 3);
                *(half8*)&sH[off] = hi;
                *(half8*)&sL[off] = lo;
            }
        }
        __syncthreads();
#pragma unroll
        for (int s = 0; s < 4; ++s) {
            const int S = (kb >> 4) + s;  // global k-step
            half8 ah = *(const half8*)&sH[((wy * 8 + 2 * s) << 8) + lane * 8];
            half8 al = *(const half8*)&sL[((wy * 8 + 2 * s) << 8) + lane * 8];
#pragma unroll
            for (int nf = 0; nf < 4; ++nf) {
                const int nblk = wx * 4 + nf;
                const size_t boff = ((size_t)(nblk * 64 + 2 * S) << 8) + lane * 8;
                half8 bh = *(const half8*)&wt_hi[boff];
                half8 bl = *(const half8*)&wt_lo[boff];
                acc[nf] = __builtin_amdgcn_mfma_f32_32x32x16_f16(ah, bh, acc[nf], 0, 0, 0);
                acc[nf] = __builtin_amdgcn_mfma_f32_32x32x16_f16(ah, bl, acc[nf], 0, 0, 0);
                acc[nf] = __builtin_amdgcn_mfma_f32_32x32x16_f16(al, bh, acc[nf], 0, 0, 0);
            }
        }
    }
    // Epilogue: C layout col=lane&31, row=(r&3)+8*(r>>2)+4*(lane>>5)
#pragma unroll
    for (int nf = 0; nf < 4; ++nf) {
        const int col = wx * 128 + nf * 32 + (lane & 31);
        const float bias = b[col];
#pragma unroll
        for (int r = 0; r < 16; ++r) {
            const int row = m0 + wy * 32 + (r & 3) + 8 * (r >> 2) + 4 * (lane >> 5);
            h[(size_t)row * DD + col] = acc[nf][r] + bias;
        }
    }
}

// ---------------------------------------------------------------------------
// Prep h: fp16 MFMA-tiled copy + row squared-norms (folds old k_rownorm).
// ht off(row,k) = ((row>>5)*32 + (k>>3))*256 + (row&31)*8 + (k&7)
// ---------------------------------------------------------------------------
__global__ __launch_bounds__(256) void k_prep_h(const float* __restrict__ h,
                                                _Float16* __restrict__ ht,
                                                float* __restrict__ hh) {
    const int lane = threadIdx.x & 63, w = threadIdx.x >> 6;
    const int row = blockIdx.x * 4 + w;
    float4v v = *(const float4v*)&h[(size_t)row * DD + lane * 4];
    half2v p0, p1;
    p0.x = (_Float16)v.x; p0.y = (_Float16)v.y;
    p1.x = (_Float16)v.z; p1.y = (_Float16)v.w;
    const size_t off = ((size_t)((row >> 5) * 32 + (lane >> 1)) << 8) +
                       ((row & 31) << 3) + ((lane & 1) << 2);
    *(half2v*)&ht[off] = p0;
    *(half2v*)&ht[off + 2] = p1;
    float s = v.x * v.x + v.y * v.y + v.z * v.z + v.w * v.w;
#pragma unroll
    for (int o = 32; o; o >>= 1) s += __shfl_down(s, o);
    if (lane == 0) hh[row] = s;
}

// ---------------------------------------------------------------------------
// Prep codebook: fp16 MFMA-tiled copy + squared norms + zero loss buckets.
// ---------------------------------------------------------------------------
__global__ __launch_bounds__(256) void k_prep_cb(const float* __restrict__ cb,
                                                 _Float16* __restrict__ cbt,
                                                 float* __restrict__ ee,
                                                 float* __restrict__ loss_part) {
    if (blockIdx.x == 0) loss_part[threadIdx.x] = 0.0f;
    const int lane = threadIdx.x & 63, w = threadIdx.x >> 6;
    const int code = blockIdx.x * 4 + w;
    float4v v = *(const float4v*)&cb[(size_t)code * DD + lane * 4];
    half2v p0, p1;
    p0.x = (_Float16)v.x; p0.y = (_Float16)v.y;
    p1.x = (_Float16)v.z; p1.y = (_Float16)v.w;
    const size_t off = ((size_t)((code >> 5) * 32 + (lane >> 1)) << 8) +
                       ((code & 31) << 3) + ((lane & 1) << 2);
    *(half2v*)&cbt[off] = p0;
    *(half2v*)&cbt[off + 2] = p1;
    float s = v.x * v.x + v.y * v.y + v.z * v.z + v.w * v.w;
#pragma unroll
    for (int o = 32; o; o >>= 1) s += __shfl_down(s, o);
    if (lane == 0) ee[code] = s;
}

// ---------------------------------------------------------------------------
// Phase 1 distance kernel — c=4 A-frags per wave (LDS-BW fix, R2).
//
// R1 post-mortem: counted-vmcnt double-buffer was NEUTRAL (132us, MfmaUtil
// 52%). Real wall: with c=2 A-frags each ds_read_b128 (1024 B) feeds only
// 2 MFMAs -> 512 LDS-B/MFMA -> demand 256 B/cyc/CU at full MFMA rate vs
// ~85-112 B/cyc supply -> util capped at ~50%. Fix: 128 codes/wave
// (afr[4][16] = 256 regs; unified 512-reg file @ 1 wave/SIMD), so each
// B-frag feeds 4 MFMAs -> 128 B/cyc demand ~= supply.
//
// Block: 512 codes x 1024 rows; 8 half-stages of 128 rows (64 KB each,
// 2 buffers = 128 KB LDS; gfx950 allows 160 KB/WG). 1 block/CU (VGPR-
// bound) -> LDS is free to use. Counted vmcnt keeps next half-stage's 16
// loads in flight across barriers; steady-state queue at the wait is
// [16 loads-t][32 stores-(t-1)][16 loads-(t+1)] -> vmcnt(48) retires
// exactly loads-t. First iter has no stores -> vmcnt(16). Tail: queue
// [16 loads-7][32 stores-6] -> vmcnt(32).
//
// A-frag k-mapping: lane L holds k = (L>>5)*8 + j  =>  byte addr must use
// lane*8 = csel*256 + lw*8 halves (R5 bug: csel*512 read the wrong k-slice).
// ee folded as a 17th k-substep: A_ext[c][0]=ee[c], B_ext[r][0]=-0.5,
// so s = ee - 2*dot = -2*acc.
// ---------------------------------------------------------------------------
__global__ __launch_bounds__(256, 1) void k_dist(const _Float16* __restrict__ ht,
                                                 const _Float16* __restrict__ cbt,
                                                 const float* __restrict__ ee,
                                                 _Float16* __restrict__ smin) {
    __shared__ _Float16 sB[2][128 * 256];  // 2 x 64 KB, tiled [rowblk4][kg32][32][8]
    const int tid = threadIdx.x, lane = tid & 63, w = tid >> 6;
    const int lw = lane & 31, csel = lane >> 5;
    const int bx = blockIdx.x;  // 512-code split (16)
    const int by = blockIdx.y;  // 1024-row split (32)

    // Load A: 4 mfrags x 16 k-substeps, each half8 (codes in lanes&31).
    half8 afr[4][16];
    const size_t lo = (size_t)lane * 8;  // = csel*256 + lw*8 (kg = 2s+csel)
#pragma unroll
    for (int mi = 0; mi < 4; ++mi) {
        const _Float16* base = cbt + (size_t)(bx * 16 + w * 4 + mi) * 8192;
#pragma unroll
        for (int s = 0; s < 16; ++s)
            afr[mi][s] = *(const half8*)(base + s * 512 + lo);
    }
    // ee-folding ext frags
    half8 aext[4], bext;
#pragma unroll
    for (int j = 0; j < 8; ++j) bext[j] = (_Float16)0.f;
    if (csel == 0) bext[0] = (_Float16)(-0.5f);
#pragma unroll
    for (int mi = 0; mi < 4; ++mi) {
        const float e = ee[bx * 512 + w * 128 + mi * 32 + lw];
#pragma unroll
        for (int j = 0; j < 8; ++j) aext[mi][j] = (_Float16)0.f;
        if (csel == 0) aext[mi][0] = (_Float16)e;
    }

    // Staging: half-stage t = 128 rows = 64 KB contiguous tiled chunk of ht;
    // wave w copies its 16 KB quarter via 16 global_load_lds dwordx4.
    const _Float16* hbase = ht + (size_t)by * 1024 * 256 + (size_t)w * 8192 + lane * 8;
#define STAGE_HS(buf, t)                                                       \
    do {                                                                       \
        const _Float16* g_ = hbase + (size_t)(t) * 32768;                      \
        char* l_ = (char*)&sB[(buf)][0] + w * 16384;                           \
        _Pragma("unroll")                                                      \
        for (int i_ = 0; i_ < 16; ++i_)                                        \
            ASYNC_CP16(g_ + i_ * 512, l_ + i_ * 1024);                         \
    } while (0)

    // Compute: 4 x 32-row njs of buffer buf, half-stage t. Per s: one
    // ds_read_b128 feeds 4 MFMAs (afr[0..3]).
#define COMPUTE_HS(buf, t)                                                     \
    do {                                                                       \
        const int r0_ = by * 1024 + (t) * 128;                                 \
        const _Float16* sb_ = &sB[(buf)][0];                                   \
        _Pragma("unroll 1")                                                    \
        for (int nj = 0; nj < 4; ++nj) {                                       \
            float16v a0 = (float16v)(0.f), a1 = (float16v)(0.f);               \
            float16v a2 = (float16v)(0.f), a3 = (float16v)(0.f);               \
            _Pragma("unroll")                                                  \
            for (int s = 0; s < 16; ++s) {                                     \
                half8 bf = *(const half8*)&sb_[(size_t)((nj * 32 + 2 * s + csel) << 8) + lw * 8]; \
                a0 = __builtin_amdgcn_mfma_f32_32x32x16_f16(afr[0][s], bf, a0, 0, 0, 0); \
                a1 = __builtin_amdgcn_mfma_f32_32x32x16_f16(afr[1][s], bf, a1, 0, 0, 0); \
                a2 = __builtin_amdgcn_mfma_f32_32x32x16_f16(afr[2][s], bf, a2, 0, 0, 0); \
                a3 = __builtin_amdgcn_mfma_f32_32x32x16_f16(afr[3][s], bf, a3, 0, 0, 0); \
            }                                                                  \
            a0 = __builtin_amdgcn_mfma_f32_32x32x16_f16(aext[0], bext, a0, 0, 0, 0); \
            a1 = __builtin_amdgcn_mfma_f32_32x32x16_f16(aext[1], bext, a1, 0, 0, 0); \
            a2 = __builtin_amdgcn_mfma_f32_32x32x16_f16(aext[2], bext, a2, 0, 0, 0); \
            a3 = __builtin_amdgcn_mfma_f32_32x32x16_f16(aext[3], bext, a3, 0, 0, 0); \
            /* Epilogue: s = -2*acc; min(s) = -2*max(acc).                  */ \
            /* C row (code) = (r&3)+8*(r>>2)+4*csel: g0 = r0..7, g1 = r8..15 */ \
            float g0a = a0[0], g1a = a0[8], g0b = a1[0], g1b = a1[8];          \
            float g0c = a2[0], g1c = a2[8], g0d = a3[0], g1d = a3[8];          \
            _Pragma("unroll")                                                  \
            for (int r = 1; r < 8; ++r) {                                      \
                g0a = fmaxf(g0a, a0[r]);  g1a = fmaxf(g1a, a0[8 + r]);         \
                g0b = fmaxf(g0b, a1[r]);  g1b = fmaxf(g1b, a1[8 + r]);         \
                g0c = fmaxf(g0c, a2[r]);  g1c = fmaxf(g1c, a2[8 + r]);         \
                g0d = fmaxf(g0d, a3[r]);  g1d = fmaxf(g1d, a3[8 + r]);         \
            }                                                                  \
            g0a = fmaxf(g0a, __shfl_xor(g0a, 32));                             \
            g1a = fmaxf(g1a, __shfl_xor(g1a, 32));                             \
            g0b = fmaxf(g0b, __shfl_xor(g0b, 32));                             \
            g1b = fmaxf(g1b, __shfl_xor(g1b, 32));                             \
            g0c = fmaxf(g0c, __shfl_xor(g0c, 32));                             \
            g1c = fmaxf(g1c, __shfl_xor(g1c, 32));                             \
            g0d = fmaxf(g0d, __shfl_xor(g0d, 32));                             \
            g1d = fmaxf(g1d, __shfl_xor(g1d, 32));                             \
            if (lane < 32) {                                                   \
                const int row_ = r0_ + nj * 32 + lane;                         \
                const int gb_ = bx * 32 + w * 8;                               \
                smin[(size_t)(gb_ + 0) * M_TOT + row_] = (_Float16)(-2.f * g0a); \
                smin[(size_t)(gb_ + 1) * M_TOT + row_] = (_Float16)(-2.f * g1a); \
                smin[(size_t)(gb_ + 2) * M_TOT + row_] = (_Float16)(-2.f * g0b); \
                smin[(size_t)(gb_ + 3) * M_TOT + row_] = (_Float16)(-2.f * g1b); \
                smin[(size_t)(gb_ + 4) * M_TOT + row_] = (_Float16)(-2.f * g0c); \
                smin[(size_t)(gb_ + 5) * M_TOT + row_] = (_Float16)(-2.f * g1c); \
                smin[(size_t)(gb_ + 6) * M_TOT + row_] = (_Float16)(-2.f * g0d); \
                smin[(size_t)(gb_ + 7) * M_TOT + row_] = (_Float16)(-2.f * g1d); \
            }                                                                  \
        }                                                                      \
    } while (0)

    // Prologue: stage half-stage 0 into buf 0.
    STAGE_HS(0, 0);

    // t=0 (no stores outstanding yet): queue = [16 loads-0][16 loads-1].
    STAGE_HS(1, 1);
    asm volatile("s_waitcnt vmcnt(16)" ::: "memory");  // loads-0 landed
    __builtin_amdgcn_s_barrier();
    __builtin_amdgcn_sched_barrier(0);
    COMPUTE_HS(0, 0);
    __builtin_amdgcn_sched_barrier(0);
    __builtin_amdgcn_s_barrier();

    // Steady state t=1..6: queue at wait =
    // [16 loads-t][32 stores-(t-1)][16 loads-(t+1)] -> vmcnt(48).
#pragma unroll 1
    for (int t = 1; t < 7; ++t) {
        const int cur = t & 1;
        STAGE_HS(cur ^ 1, t + 1);
        asm volatile("s_waitcnt vmcnt(48)" ::: "memory");  // loads-t landed
        __builtin_amdgcn_s_barrier();
        __builtin_amdgcn_sched_barrier(0);
        COMPUTE_HS(cur, t);
        __builtin_amdgcn_sched_barrier(0);
        __builtin_amdgcn_s_barrier();
    }
    // Tail t=7: queue = [16 loads-7][32 stores-6] -> vmcnt(32).
    asm volatile("s_waitcnt vmcnt(32)" ::: "memory");
    __builtin_amdgcn_s_barrier();
    __builtin_amdgcn_sched_barrier(0);
    COMPUTE_HS(1, 7);

#undef STAGE_HS
#undef COMPUTE_HS
}

// ---------------------------------------------------------------------------
// Phase 2: wave-per-row (verified R4). LDS-transpose 64-row slab of smin_T,
// margin-filter granules, exact fp32 rescore ((hh+ee)-2*dot, lowest-index
// tie-break), gather zq, write out, bucketized loss.
// ---------------------------------------------------------------------------
__global__ __launch_bounds__(256, 2) void k_select(const float* __restrict__ h,
                                                   const float* __restrict__ cb,
                                                   const float* __restrict__ hh,
                                                   const float* __restrict__ ee,
                                                   const _Float16* __restrict__ smin,
                                                   float* __restrict__ out,
                                                   float* __restrict__ loss_part) {
    __shared__ _Float16 sS[64][512];  // [row][granule] = 64 KB
    const int t = threadIdx.x, lane = t & 63, w = t >> 6;
    const int r0 = blockIdx.x * 64;

    for (int gi = t; gi < NGRAN; gi += 256) {
        const _Float16* src = smin + (size_t)gi * M_TOT + r0;
#pragma unroll
        for (int c = 0; c < 8; ++c) {
            half8 v = *(const half8*)(src + c * 8);
#pragma unroll
            for (int j = 0; j < 8; ++j) sS[c * 8 + j][gi] = v[j];
        }
    }
    __syncthreads();

    float lossacc = 0.0f;
    for (int i = 0; i < 16; ++i) {
        const int row = r0 + w * 16 + i;
        float4v hv = *(const float4v*)&h[(size_t)row * DD + lane * 4];
        half8 sm = *(const half8*)&sS[w * 16 + i][lane * 8];
        float vmin = 1e30f;
        float sv[8];
#pragma unroll
        for (int j = 0; j < 8; ++j) {
            sv[j] = (float)sm[j];
            vmin = fminf(vmin, sv[j]);
        }
        float m2 = vmin;
#pragma unroll
        for (int o = 32; o; o >>= 1) m2 = fminf(m2, __shfl_xor(m2, o));
        const float thr = m2 + MARGIN;
        unsigned flags = 0;
#pragma unroll
        for (int j = 0; j < 8; ++j)
            if (sv[j] <= thr) flags |= (1u << j);

        unsigned long long act = __ballot(flags != 0);
        unsigned long long bestk = ~0ull;
        const float hhv = hh[row];
        while (act) {
            const int ln = __ffsll((long long)act) - 1;
            act &= act - 1;
            unsigned fl = (unsigned)__shfl((int)flags, ln);
            while (fl) {
                const int j = __ffs(fl) - 1;
                fl &= fl - 1;
                const int g = ln * 8 + j;
#pragma unroll
                for (int c = 0; c < 16; ++c) {
                    const int code = g * 16 + c;
                    float4v cv = *(const float4v*)&cb[(size_t)code * DD + lane * 4];
                    float s = hv.x * cv.x + hv.y * cv.y + hv.z * cv.z + hv.w * cv.w;
#pragma unroll
                    for (int o = 32; o; o >>= 1) s += __shfl_xor(s, o);
                    const float d = (hhv + ee[code]) - 2.0f * s;  // reference formula
                    const unsigned bts = __float_as_uint(d);
                    const unsigned mb =
                        bts ^ (unsigned)(((int)bts >> 31) | 0x80000000);
                    const unsigned long long key =
                        ((unsigned long long)mb << 32) | (unsigned)code;
                    if (key < bestk) bestk = key;
                }
            }
        }
        const unsigned best = (unsigned)(bestk & 0xffffffffull);
        float4v cv = *(const float4v*)&cb[(size_t)best * DD + lane * 4];
        *(float4v*)&out[(size_t)row * DD + lane * 4] = cv;
        const float dx = cv.x - hv.x, dy = cv.y - hv.y;
        const float dz = cv.z - hv.z, dw = cv.w - hv.w;
        lossacc += dx * dx + dy * dy + dz * dz + dw * dw;
    }
#pragma unroll
    for (int o = 32; o; o >>= 1) lossacc += __shfl_xor(lossacc, o);
    if (lane == 0)
        atomicAdd(&loss_part[(blockIdx.x * 4 + w) & (NBUCKET - 1)], lossacc);
}

__global__ __launch_bounds__(256) void k_final(const float* __restrict__ loss_part,
                                               float* __restrict__ out) {
    const int t = threadIdx.x;
    float s = loss_part[t];
#pragma unroll
    for (int off = 32; off; off >>= 1) s += __shfl_down(s, off);
    __shared__ float wsum[4];
    if ((t & 63) == 0) wsum[t >> 6] = s;
    __syncthreads();
    if (t == 0)
        out[0] = 1.25f * ((wsum[0] + wsum[1]) + (wsum[2] + wsum[3]))
                 / (float)(M_TOT * DD);  // BETA*mean + mean
}

// ---------------------------------------------------------------------------
extern "C" void kernel_launch(void* const* d_in, const int* in_sizes, int n_in,
                              void* d_out, int out_size, void* d_ws, size_t ws_size,
                              hipStream_t stream) {
    const float* x  = (const float*)d_in[0];
    const float* W  = (const float*)d_in[1];
    const float* b  = (const float*)d_in[2];
    const float* cb = (const float*)d_in[3];
    float* out = (float*)d_out;

    char* ws = (char*)d_ws;
    float* h        = (float*)(ws + OFF_H);
    _Float16* ht    = (_Float16*)(ws + OFF_HT);
    _Float16* cbt   = (_Float16*)(ws + OFF_CBT);
    _Float16* wt_hi = (_Float16*)(ws + OFF_WTH);
    _Float16* wt_lo = (_Float16*)(ws + OFF_WTL);
    float* hh       = (float*)(ws + OFF_HH);
    float* ee       = (float*)(ws + OFF_EE);
    _Float16* smin  = (_Float16*)(ws + OFF_SMIN);
    float* loss_part = (float*)(ws + OFF_LOSSP);

    hipLaunchKernelGGL(k_prep_w, dim3(512), dim3(256), 0, stream, W, wt_hi, wt_lo);
    hipLaunchKernelGGL(k_prep_cb, dim3(KCODES / 4), dim3(256), 0, stream,
                       cb, cbt, ee, loss_part);
    hipLaunchKernelGGL(k_gemm1, dim3(M_TOT / 64), dim3(256), 0, stream,
                       x, wt_hi, wt_lo, b, h);
    hipLaunchKernelGGL(k_prep_h, dim3(M_TOT / 4), dim3(256), 0, stream,
                       h, ht, hh);
    hipLaunchKernelGGL(k_dist, dim3(KCODES / 512, M_TOT / 1024), dim3(256),
                       0, stream, ht, cbt, ee, smin);
    hipLaunchKernelGGL(k_select, dim3(M_TOT / 64), dim3(256), 0, stream,
                       h, cb, hh, ee, smin, out, loss_part);
    hipLaunchKernelGGL(k_final, dim3(1), dim3(256), 0, stream,
                       loss_part, out + (size_t)M_TOT * DD);
}

// Round 3
// 370.434 us; speedup vs baseline: 1.0162x; 1.0162x over previous
//
#include <hip/hip_runtime.h>
#include <stdint.h>

// Problem constants (B=8, T=4096, Zc=512, D=256, K=8192)
#define M_TOT 32768
#define ZC 512
#define DD 256
#define KCODES 8192
#define NGRAN 512            // KCODES / 16 codes per granule
#define MARGIN 0.15f         // >2x hard fp16-error bound (validated R2/R3/R4)
#define NBUCKET 256

typedef _Float16 half8   __attribute__((ext_vector_type(8)));
typedef _Float16 half2v  __attribute__((ext_vector_type(2)));
typedef float    float4v __attribute__((ext_vector_type(4)));
typedef float    float16v __attribute__((ext_vector_type(16)));

// Workspace layout (bytes). wt_hi/wt_lo overlap smin: prep_w/gemm1 finish
// before k_dist writes smin (stream-ordered, every launch identical).
#define OFF_H     0ull                  // h fp32: 32 MB
#define OFF_HT    33554432ull           // ht fp16 tiled: 16 MB
#define OFF_CBT   50331648ull           // cbt fp16 tiled: 4 MB
#define OFF_HH    54525952ull           // hh: 128 KB
#define OFF_EE    54657024ull           // ee: 32 KB
#define OFF_LOSSP 54689792ull           // loss buckets: 1 KB
#define OFF_SMIN  54691840ull           // smin_T fp16 [NGRAN][M_TOT]: 32 MB
#define OFF_WTH   OFF_SMIN              // Wt_hi fp16 tiled: 512 KB (overlap)
#define OFF_WTL   (OFF_SMIN + 524288ull) // Wt_lo fp16 tiled: 512 KB (overlap)

// async global->LDS, 16B per lane, LDS dst = wave-uniform base + lane*16
#define ASYNC_CP16(gp, lp)                                                     \
  __builtin_amdgcn_global_load_lds(                                            \
      (const __attribute__((address_space(1))) void*)(gp),                     \
      (__attribute__((address_space(3))) void*)(lp), 16, 0, 0)

// ---------------------------------------------------------------------------
// Prep W: split-fp16 (hi+lo) of W[512][256], stored MFMA-B-tiled:
// off(n,k) = ((n>>5)*64 + (k>>3))*256 + (n&31)*8 + (k&7)
// ---------------------------------------------------------------------------
__global__ __launch_bounds__(256) void k_prep_w(const float* __restrict__ W,
                                                _Float16* __restrict__ wt_hi,
                                                _Float16* __restrict__ wt_lo) {
    const int idx = blockIdx.x * 256 + threadIdx.x;  // 131072
    const int n = idx & 255, k = idx >> 8;
    const float v = W[(size_t)k * DD + n];
    const _Float16 hi = (_Float16)v;
    const _Float16 lo = (_Float16)(v - (float)hi);
    const int off = (((n >> 5) * 64 + (k >> 3)) << 8) + ((n & 31) << 3) + (k & 7);
    wt_hi[off] = hi;
    wt_lo[off] = lo;
}

// ---------------------------------------------------------------------------
// K1: h = x@W + b via split-fp16 MFMA (hi*hi + hi*lo + lo*hi). Verified R4.
// ---------------------------------------------------------------------------
__global__ __launch_bounds__(256) void k_gemm1(const float* __restrict__ x,
                                               const _Float16* __restrict__ wt_hi,
                                               const _Float16* __restrict__ wt_lo,
                                               const float* __restrict__ b,
                                               float* __restrict__ h) {
    __shared__ _Float16 sH[64 * 64];  // tiled [mblk2][kg8][32][8]
    __shared__ _Float16 sL[64 * 64];
    const int tid = threadIdx.x, lane = tid & 63, w = tid >> 6;
    const int wy = w >> 1, wx = w & 1;
    const int m0 = blockIdx.x * 64;

    float16v acc[4];
#pragma unroll
    for (int j = 0; j < 4; ++j) acc[j] = (float16v)(0.0f);

    for (int kb = 0; kb < ZC; kb += 64) {
        __syncthreads();
        {
            const int m = tid & 63;
            const int kp = tid >> 6;  // 0..3
#pragma unroll
            for (int i2 = 0; i2 < 2; ++i2) {
                const int kg = kp * 2 + i2;
                const float* src = x + (size_t)(m0 + m) * ZC + kb + kg * 8;
                float4v v0 = *(const float4v*)src;
                float4v v1 = *(const float4v*)(src + 4);
                half8 hi, lo;
                float vv[8] = {v0.x, v0.y, v0.z, v0.w, v1.x, v1.y, v1.z, v1.w};
#pragma unroll
                for (int j = 0; j < 8; ++j) {
                    hi[j] = (_Float16)vv[j];
                    lo[j] = (_Float16)(vv[j] - (float)hi[j]);
                }
                const int off = (((m >> 5) * 8 + kg) << 8) + ((m & 31) << 3);
                *(half8*)&sH[off] = hi;
                *(half8*)&sL[off] = lo;
            }
        }
        __syncthreads();
#pragma unroll
        for (int s = 0; s < 4; ++s) {
            const int S = (kb >> 4) + s;  // global k-step
            half8 ah = *(const half8*)&sH[((wy * 8 + 2 * s) << 8) + lane * 8];
            half8 al = *(const half8*)&sL[((wy * 8 + 2 * s) << 8) + lane * 8];
#pragma unroll
            for (int nf = 0; nf < 4; ++nf) {
                const int nblk = wx * 4 + nf;
                const size_t boff = ((size_t)(nblk * 64 + 2 * S) << 8) + lane * 8;
                half8 bh = *(const half8*)&wt_hi[boff];
                half8 bl = *(const half8*)&wt_lo[boff];
                acc[nf] = __builtin_amdgcn_mfma_f32_32x32x16_f16(ah, bh, acc[nf], 0, 0, 0);
                acc[nf] = __builtin_amdgcn_mfma_f32_32x32x16_f16(ah, bl, acc[nf], 0, 0, 0);
                acc[nf] = __builtin_amdgcn_mfma_f32_32x32x16_f16(al, bh, acc[nf], 0, 0, 0);
            }
        }
    }
    // Epilogue: C layout col=lane&31, row=(r&3)+8*(r>>2)+4*(lane>>5)
#pragma unroll
    for (int nf = 0; nf < 4; ++nf) {
        const int col = wx * 128 + nf * 32 + (lane & 31);
        const float bias = b[col];
#pragma unroll
        for (int r = 0; r < 16; ++r) {
            const int row = m0 + wy * 32 + (r & 3) + 8 * (r >> 2) + 4 * (lane >> 5);
            h[(size_t)row * DD + col] = acc[nf][r] + bias;
        }
    }
}

// ---------------------------------------------------------------------------
// Prep h: fp16 MFMA-tiled copy + row squared-norms (folds old k_rownorm).
// ht off(row,k) = ((row>>5)*32 + (k>>3))*256 + (row&31)*8 + (k&7)
// ---------------------------------------------------------------------------
__global__ __launch_bounds__(256) void k_prep_h(const float* __restrict__ h,
                                                _Float16* __restrict__ ht,
                                                float* __restrict__ hh) {
    const int lane = threadIdx.x & 63, w = threadIdx.x >> 6;
    const int row = blockIdx.x * 4 + w;
    float4v v = *(const float4v*)&h[(size_t)row * DD + lane * 4];
    half2v p0, p1;
    p0.x = (_Float16)v.x; p0.y = (_Float16)v.y;
    p1.x = (_Float16)v.z; p1.y = (_Float16)v.w;
    const size_t off = ((size_t)((row >> 5) * 32 + (lane >> 1)) << 8) +
                       ((row & 31) << 3) + ((lane & 1) << 2);
    *(half2v*)&ht[off] = p0;
    *(half2v*)&ht[off + 2] = p1;
    float s = v.x * v.x + v.y * v.y + v.z * v.z + v.w * v.w;
#pragma unroll
    for (int o = 32; o; o >>= 1) s += __shfl_down(s, o);
    if (lane == 0) hh[row] = s;
}

// ---------------------------------------------------------------------------
// Prep codebook: fp16 MFMA-tiled copy + squared norms + zero loss buckets.
// ---------------------------------------------------------------------------
__global__ __launch_bounds__(256) void k_prep_cb(const float* __restrict__ cb,
                                                 _Float16* __restrict__ cbt,
                                                 float* __restrict__ ee,
                                                 float* __restrict__ loss_part) {
    if (blockIdx.x == 0) loss_part[threadIdx.x] = 0.0f;
    const int lane = threadIdx.x & 63, w = threadIdx.x >> 6;
    const int code = blockIdx.x * 4 + w;
    float4v v = *(const float4v*)&cb[(size_t)code * DD + lane * 4];
    half2v p0, p1;
    p0.x = (_Float16)v.x; p0.y = (_Float16)v.y;
    p1.x = (_Float16)v.z; p1.y = (_Float16)v.w;
    const size_t off = ((size_t)((code >> 5) * 32 + (lane >> 1)) << 8) +
                       ((code & 31) << 3) + ((lane & 1) << 2);
    *(half2v*)&cbt[off] = p0;
    *(half2v*)&cbt[off + 2] = p1;
    float s = v.x * v.x + v.y * v.y + v.z * v.z + v.w * v.w;
#pragma unroll
    for (int o = 32; o; o >>= 1) s += __shfl_down(s, o);
    if (lane == 0) ee[code] = s;
}

// ---------------------------------------------------------------------------
// Phase 1 distance kernel — R3: software-pipelined B-fragment reads.
//
// R2 post-mortem: c=4 regressed (146us, MfmaUtil 44.6%, occ 10.8%) — reg
// pressure cut occupancy to 1 wave/SIMD, killing pipe overlap; LDS BW was
// never binding. R0/R1 post-mortem: sum-of-pipes (MFMA 58 + LDS 41 + VALU
// 26 us) ~= wall 133us -> pipes fully SERIALIZED (phase-locked waves:
// [16 ds_read][34 MFMA][epilogue] in lockstep).
//
// Fix: within-wave modulo schedule. Each nj = 4 chunks x 4 s-steps; issue
// chunk c+1's 4 ds_read_b128 into the ping-pong buffer BEFORE chunk c's 8
// MFMAs (compiler emits counted lgkmcnt; reads stream on LDS pipe under
// MFMA pipe time). Across nj: prefetch nj+1 chunk 0 before nj's epilogue,
// so epilogue VALU+stores overlap those reads. setprio(1) around MFMA
// clusters (waves desync in the barrier-free stage -> role diversity).
// Geometry back to R1: c=2 (afr[2][16]=128 regs), 64-row half-stages,
// dbuf 2x32KB, 2 blocks/CU. +16 VGPR for bfA/bfB.
//
// Staging: counted vmcnt, corrected counts. Queue at iter-t wait (steady):
// [8 loads-t][8 stores-(t-1)][8 loads-(t+1)] -> vmcnt(16) retires exactly
// loads-t. t=0: [8 loads-0][8 loads-1] -> vmcnt(8). Tail t=15:
// [8 loads-15][8 stores-14] -> vmcnt(8).
//
// A-frag k-mapping: lane L holds k = (L>>5)*8 + j  =>  byte addr must use
// lane*8 = csel*256 + lw*8 halves (R5 bug: csel*512 read the wrong k-slice).
// ee folded as a 17th k-substep: A_ext[c][0]=ee[c], B_ext[r][0]=-0.5,
// so s = ee - 2*dot = -2*acc.
// ---------------------------------------------------------------------------
__global__ __launch_bounds__(256, 2) void k_dist(const _Float16* __restrict__ ht,
                                                 const _Float16* __restrict__ cbt,
                                                 const float* __restrict__ ee,
                                                 _Float16* __restrict__ smin) {
    __shared__ _Float16 sB[2][64 * 256];  // 2 x 32 KB, tiled [rowblk2][kg32][32][8]
    const int tid = threadIdx.x, lane = tid & 63, w = tid >> 6;
    const int lw = lane & 31, csel = lane >> 5;
    const int bx = blockIdx.x;  // 256-code split (32)
    const int by = blockIdx.y;  // 1024-row split (32)

    // Load A: 2 mfrags x 16 k-substeps, each half8 (codes in lanes&31).
    half8 afr[2][16];
    const size_t lo = (size_t)lane * 8;  // = csel*256 + lw*8 (kg = 2s+csel)
#pragma unroll
    for (int mi = 0; mi < 2; ++mi) {
        const _Float16* base = cbt + (size_t)(bx * 8 + w * 2 + mi) * 8192;
#pragma unroll
        for (int s = 0; s < 16; ++s)
            afr[mi][s] = *(const half8*)(base + s * 512 + lo);
    }
    // ee-folding ext frags
    half8 aext[2], bext;
#pragma unroll
    for (int j = 0; j < 8; ++j) bext[j] = (_Float16)0.f;
    if (csel == 0) bext[0] = (_Float16)(-0.5f);
#pragma unroll
    for (int mi = 0; mi < 2; ++mi) {
        const float e = ee[bx * 256 + w * 64 + mi * 32 + lw];
#pragma unroll
        for (int j = 0; j < 8; ++j) aext[mi][j] = (_Float16)0.f;
        if (csel == 0) aext[mi][0] = (_Float16)e;
    }

    // Staging: half-stage t = 64 rows = 32 KB; wave copies its 8 KB quarter
    // via 8 global_load_lds dwordx4 (wave-uniform LDS base + lane*16).
    const _Float16* hbase = ht + (size_t)by * 1024 * 256 + (size_t)w * 4096 + lane * 8;
#define STAGE_HS(buf, t)                                                       \
    do {                                                                       \
        const _Float16* g_ = hbase + (size_t)(t) * 16384;                      \
        char* l_ = (char*)&sB[(buf)][0] + w * 8192;                            \
        _Pragma("unroll")                                                      \
        for (int i_ = 0; i_ < 8; ++i_)                                         \
            ASYNC_CP16(g_ + i_ * 512, l_ + i_ * 1024);                         \
    } while (0)

    // B-fragment read: nj in {0,1}, s in {0..15}.
#define LDB(sb_, nj_, s_)                                                      \
    (*(const half8*)&(sb_)[(size_t)((((nj_) * 32) + 2 * (s_) + csel) << 8) + lw * 8])

#define RD4(sb_, dst, nj_, s0)                                                 \
    do {                                                                       \
        dst[0] = LDB(sb_, nj_, (s0) + 0);                                      \
        dst[1] = LDB(sb_, nj_, (s0) + 1);                                      \
        dst[2] = LDB(sb_, nj_, (s0) + 2);                                      \
        dst[3] = LDB(sb_, nj_, (s0) + 3);                                      \
    } while (0)

#define MM8(bfv, s0)                                                           \
    do {                                                                       \
        __builtin_amdgcn_s_setprio(1);                                         \
        acc0 = __builtin_amdgcn_mfma_f32_32x32x16_f16(afr[0][(s0) + 0], bfv[0], acc0, 0, 0, 0); \
        acc1 = __builtin_amdgcn_mfma_f32_32x32x16_f16(afr[1][(s0) + 0], bfv[0], acc1, 0, 0, 0); \
        acc0 = __builtin_amdgcn_mfma_f32_32x32x16_f16(afr[0][(s0) + 1], bfv[1], acc0, 0, 0, 0); \
        acc1 = __builtin_amdgcn_mfma_f32_32x32x16_f16(afr[1][(s0) + 1], bfv[1], acc1, 0, 0, 0); \
        acc0 = __builtin_amdgcn_mfma_f32_32x32x16_f16(afr[0][(s0) + 2], bfv[2], acc0, 0, 0, 0); \
        acc1 = __builtin_amdgcn_mfma_f32_32x32x16_f16(afr[1][(s0) + 2], bfv[2], acc1, 0, 0, 0); \
        acc0 = __builtin_amdgcn_mfma_f32_32x32x16_f16(afr[0][(s0) + 3], bfv[3], acc0, 0, 0, 0); \
        acc1 = __builtin_amdgcn_mfma_f32_32x32x16_f16(afr[1][(s0) + 3], bfv[3], acc1, 0, 0, 0); \
        __builtin_amdgcn_s_setprio(0);                                         \
    } while (0)

#define MMEXT()                                                                \
    do {                                                                       \
        acc0 = __builtin_amdgcn_mfma_f32_32x32x16_f16(aext[0], bext, acc0, 0, 0, 0); \
        acc1 = __builtin_amdgcn_mfma_f32_32x32x16_f16(aext[1], bext, acc1, 0, 0, 0); \
    } while (0)

    // Epilogue: s = -2*acc; min(s) = -2*max(acc).
    // C row (code) = (r&3)+8*(r>>2)+4*csel: granule0 = r 0..7, g1 = r 8..15.
#define EPI(nj_)                                                               \
    do {                                                                       \
        float g0a = acc0[0], g1a = acc0[8];                                    \
        float g0b = acc1[0], g1b = acc1[8];                                    \
        _Pragma("unroll")                                                      \
        for (int r = 1; r < 8; ++r) {                                          \
            g0a = fmaxf(g0a, acc0[r]);  g1a = fmaxf(g1a, acc0[8 + r]);         \
            g0b = fmaxf(g0b, acc1[r]);  g1b = fmaxf(g1b, acc1[8 + r]);         \
        }                                                                      \
        g0a = fmaxf(g0a, __shfl_xor(g0a, 32));                                 \
        g1a = fmaxf(g1a, __shfl_xor(g1a, 32));                                 \
        g0b = fmaxf(g0b, __shfl_xor(g0b, 32));                                 \
        g1b = fmaxf(g1b, __shfl_xor(g1b, 32));                                 \
        if (lane < 32) {                                                       \
            const int row_ = r0_ + (nj_) * 32 + lane;                          \
            const int gb_ = bx * 16 + w * 4;                                   \
            smin[(size_t)(gb_ + 0) * M_TOT + row_] = (_Float16)(-2.f * g0a);   \
            smin[(size_t)(gb_ + 1) * M_TOT + row_] = (_Float16)(-2.f * g1a);   \
            smin[(size_t)(gb_ + 2) * M_TOT + row_] = (_Float16)(-2.f * g0b);   \
            smin[(size_t)(gb_ + 3) * M_TOT + row_] = (_Float16)(-2.f * g1b);   \
        }                                                                      \
    } while (0)

    // Compute one half-stage (64 rows = 2 njs), chunk-pipelined.
#define COMPUTE_HS(buf, t)                                                     \
    do {                                                                       \
        const int r0_ = by * 1024 + (t) * 64;                                  \
        const _Float16* sb_ = &sB[(buf)][0];                                   \
        half8 bfA[4], bfB[4];                                                  \
        float16v acc0 = (float16v)(0.f), acc1 = (float16v)(0.f);               \
        /* nj 0 */                                                             \
        RD4(sb_, bfA, 0, 0);                                                   \
        RD4(sb_, bfB, 0, 4);   MM8(bfA, 0);                                    \
        RD4(sb_, bfA, 0, 8);   MM8(bfB, 4);                                    \
        RD4(sb_, bfB, 0, 12);  MM8(bfA, 8);                                    \
        RD4(sb_, bfA, 1, 0);   MM8(bfB, 12);  /* prefetch nj1.c0 */            \
        MMEXT();                                                               \
        EPI(0);                       /* overlaps nj1.c0 reads in flight */    \
        /* nj 1 */                                                             \
        acc0 = (float16v)(0.f); acc1 = (float16v)(0.f);                        \
        RD4(sb_, bfB, 1, 4);   MM8(bfA, 0);                                    \
        RD4(sb_, bfA, 1, 8);   MM8(bfB, 4);                                    \
        RD4(sb_, bfB, 1, 12);  MM8(bfA, 8);                                    \
        MM8(bfB, 12);                                                          \
        MMEXT();                                                               \
        EPI(1);                                                                \
    } while (0)

    // Prologue: stage half-stages 0 and 1.
    STAGE_HS(0, 0);
    STAGE_HS(1, 1);
    // t=0: queue = [8 loads-0][8 loads-1] -> vmcnt(8) retires loads-0.
    asm volatile("s_waitcnt vmcnt(8)" ::: "memory");
    __builtin_amdgcn_s_barrier();
    __builtin_amdgcn_sched_barrier(0);
    COMPUTE_HS(0, 0);
    __builtin_amdgcn_sched_barrier(0);
    __builtin_amdgcn_s_barrier();

    // Steady state t=1..14: queue at wait =
    // [8 loads-t][8 stores-(t-1)][8 loads-(t+1)] -> vmcnt(16).
#pragma unroll 1
    for (int t = 1; t < 15; ++t) {
        const int cur = t & 1;
        STAGE_HS(cur ^ 1, t + 1);
        asm volatile("s_waitcnt vmcnt(16)" ::: "memory");  // loads-t landed
        __builtin_amdgcn_s_barrier();
        __builtin_amdgcn_sched_barrier(0);
        COMPUTE_HS(cur, t);
        __builtin_amdgcn_sched_barrier(0);
        __builtin_amdgcn_s_barrier();
    }
    // Tail t=15: queue = [8 loads-15][8 stores-14] -> vmcnt(8).
    asm volatile("s_waitcnt vmcnt(8)" ::: "memory");
    __builtin_amdgcn_s_barrier();
    __builtin_amdgcn_sched_barrier(0);
    COMPUTE_HS(1, 15);

#undef STAGE_HS
#undef COMPUTE_HS
#undef LDB
#undef RD4
#undef MM8
#undef MMEXT
#undef EPI
}

// ---------------------------------------------------------------------------
// Phase 2: wave-per-row (verified R4). LDS-transpose 64-row slab of smin_T,
// margin-filter granules, exact fp32 rescore ((hh+ee)-2*dot, lowest-index
// tie-break), gather zq, write out, bucketized loss.
// ---------------------------------------------------------------------------
__global__ __launch_bounds__(256, 2) void k_select(const float* __restrict__ h,
                                                   const float* __restrict__ cb,
                                                   const float* __restrict__ hh,
                                                   const float* __restrict__ ee,
                                                   const _Float16* __restrict__ smin,
                                                   float* __restrict__ out,
                                                   float* __restrict__ loss_part) {
    __shared__ _Float16 sS[64][512];  // [row][granule] = 64 KB
    const int t = threadIdx.x, lane = t & 63, w = t >> 6;
    const int r0 = blockIdx.x * 64;

    for (int gi = t; gi < NGRAN; gi += 256) {
        const _Float16* src = smin + (size_t)gi * M_TOT + r0;
#pragma unroll
        for (int c = 0; c < 8; ++c) {
            half8 v = *(const half8*)(src + c * 8);
#pragma unroll
            for (int j = 0; j < 8; ++j) sS[c * 8 + j][gi] = v[j];
        }
    }
    __syncthreads();

    float lossacc = 0.0f;
    for (int i = 0; i < 16; ++i) {
        const int row = r0 + w * 16 + i;
        float4v hv = *(const float4v*)&h[(size_t)row * DD + lane * 4];
        half8 sm = *(const half8*)&sS[w * 16 + i][lane * 8];
        float vmin = 1e30f;
        float sv[8];
#pragma unroll
        for (int j = 0; j < 8; ++j) {
            sv[j] = (float)sm[j];
            vmin = fminf(vmin, sv[j]);
        }
        float m2 = vmin;
#pragma unroll
        for (int o = 32; o; o >>= 1) m2 = fminf(m2, __shfl_xor(m2, o));
        const float thr = m2 + MARGIN;
        unsigned flags = 0;
#pragma unroll
        for (int j = 0; j < 8; ++j)
            if (sv[j] <= thr) flags |= (1u << j);

        unsigned long long act = __ballot(flags != 0);
        unsigned long long bestk = ~0ull;
        const float hhv = hh[row];
        while (act) {
            const int ln = __ffsll((long long)act) - 1;
            act &= act - 1;
            unsigned fl = (unsigned)__shfl((int)flags, ln);
            while (fl) {
                const int j = __ffs(fl) - 1;
                fl &= fl - 1;
                const int g = ln * 8 + j;
#pragma unroll
                for (int c = 0; c < 16; ++c) {
                    const int code = g * 16 + c;
                    float4v cv = *(const float4v*)&cb[(size_t)code * DD + lane * 4];
                    float s = hv.x * cv.x + hv.y * cv.y + hv.z * cv.z + hv.w * cv.w;
#pragma unroll
                    for (int o = 32; o; o >>= 1) s += __shfl_xor(s, o);
                    const float d = (hhv + ee[code]) - 2.0f * s;  // reference formula
                    const unsigned bts = __float_as_uint(d);
                    const unsigned mb =
                        bts ^ (unsigned)(((int)bts >> 31) | 0x80000000);
                    const unsigned long long key =
                        ((unsigned long long)mb << 32) | (unsigned)code;
                    if (key < bestk) bestk = key;
                }
            }
        }
        const unsigned best = (unsigned)(bestk & 0xffffffffull);
        float4v cv = *(const float4v*)&cb[(size_t)best * DD + lane * 4];
        *(float4v*)&out[(size_t)row * DD + lane * 4] = cv;
        const float dx = cv.x - hv.x, dy = cv.y - hv.y;
        const float dz = cv.z - hv.z, dw = cv.w - hv.w;
        lossacc += dx * dx + dy * dy + dz * dz + dw * dw;
    }
#pragma unroll
    for (int o = 32; o; o >>= 1) lossacc += __shfl_xor(lossacc, o);
    if (lane == 0)
        atomicAdd(&loss_part[(blockIdx.x * 4 + w) & (NBUCKET - 1)], lossacc);
}

__global__ __launch_bounds__(256) void k_final(const float* __restrict__ loss_part,
                                               float* __restrict__ out) {
    const int t = threadIdx.x;
    float s = loss_part[t];
#pragma unroll
    for (int off = 32; off; off >>= 1) s += __shfl_down(s, off);
    __shared__ float wsum[4];
    if ((t & 63) == 0) wsum[t >> 6] = s;
    __syncthreads();
    if (t == 0)
        out[0] = 1.25f * ((wsum[0] + wsum[1]) + (wsum[2] + wsum[3]))
                 / (float)(M_TOT * DD);  // BETA*mean + mean
}

// ---------------------------------------------------------------------------
extern "C" void kernel_launch(void* const* d_in, const int* in_sizes, int n_in,
                              void* d_out, int out_size, void* d_ws, size_t ws_size,
                              hipStream_t stream) {
    const float* x  = (const float*)d_in[0];
    const float* W  = (const float*)d_in[1];
    const float* b  = (const float*)d_in[2];
    const float* cb = (const float*)d_in[3];
    float* out = (float*)d_out;

    char* ws = (char*)d_ws;
    float* h        = (float*)(ws + OFF_H);
    _Float16* ht    = (_Float16*)(ws + OFF_HT);
    _Float16* cbt   = (_Float16*)(ws + OFF_CBT);
    _Float16* wt_hi = (_Float16*)(ws + OFF_WTH);
    _Float16* wt_lo = (_Float16*)(ws + OFF_WTL);
    float* hh       = (float*)(ws + OFF_HH);
    float* ee       = (float*)(ws + OFF_EE);
    _Float16* smin  = (_Float16*)(ws + OFF_SMIN);
    float* loss_part = (float*)(ws + OFF_LOSSP);

    hipLaunchKernelGGL(k_prep_w, dim3(512), dim3(256), 0, stream, W, wt_hi, wt_lo);
    hipLaunchKernelGGL(k_prep_cb, dim3(KCODES / 4), dim3(256), 0, stream,
                       cb, cbt, ee, loss_part);
    hipLaunchKernelGGL(k_gemm1, dim3(M_TOT / 64), dim3(256), 0, stream,
                       x, wt_hi, wt_lo, b, h);
    hipLaunchKernelGGL(k_prep_h, dim3(M_TOT / 4), dim3(256), 0, stream,
                       h, ht, hh);
    hipLaunchKernelGGL(k_dist, dim3(KCODES / 256, M_TOT / 1024), dim3(256),
                       0, stream, ht, cbt, ee, smin);
    hipLaunchKernelGGL(k_select, dim3(M_TOT / 64), dim3(256), 0, stream,
                       h, cb, hh, ee, smin, out, loss_part);
    hipLaunchKernelGGL(k_final, dim3(1), dim3(256), 0, stream,
                       loss_part, out + (size_t)M_TOT * DD);
}

// Round 6
// 367.163 us; speedup vs baseline: 1.0253x; 1.0089x over previous
//
#include <hip/hip_runtime.h>
#include <stdint.h>

// Problem constants (B=8, T=4096, Zc=512, D=256, K=8192)
#define M_TOT 32768
#define ZC 512
#define DD 256
#define KCODES 8192
#define NGRAN 512            // KCODES / 16 codes per granule
#define MARGIN 0.15f         // >2x hard fp16-error bound (validated R2/R3/R4)
#define NBUCKET 256

typedef _Float16 half8   __attribute__((ext_vector_type(8)));
typedef _Float16 half2v  __attribute__((ext_vector_type(2)));
typedef float    float4v __attribute__((ext_vector_type(4)));
typedef float    float16v __attribute__((ext_vector_type(16)));

// Workspace layout (bytes). wt_hi/wt_lo overlap smin: prep_w/gemm1 finish
// before k_dist writes smin (stream-ordered, every launch identical).
#define OFF_H     0ull                  // h fp32: 32 MB
#define OFF_HT    33554432ull           // ht fp16 tiled: 16 MB
#define OFF_CBT   50331648ull           // cbt fp16 tiled: 4 MB
#define OFF_HH    54525952ull           // hh: 128 KB
#define OFF_EE    54657024ull           // ee: 32 KB
#define OFF_LOSSP 54689792ull           // loss buckets: 1 KB
#define OFF_SMIN  54691840ull           // smin_T fp16 [NGRAN][M_TOT]: 32 MB
#define OFF_WTH   OFF_SMIN              // Wt_hi fp16 tiled: 512 KB (overlap)
#define OFF_WTL   (OFF_SMIN + 524288ull) // Wt_lo fp16 tiled: 512 KB (overlap)

// async global->LDS, 16B per lane, LDS dst = wave-uniform base + lane*16
#define ASYNC_CP16(gp, lp)                                                     \
  __builtin_amdgcn_global_load_lds(                                            \
      (const __attribute__((address_space(1))) void*)(gp),                     \
      (__attribute__((address_space(3))) void*)(lp), 16, 0, 0)

// ---------------------------------------------------------------------------
// Prep W: split-fp16 (hi+lo) of W[512][256], stored MFMA-B-tiled:
// off(n,k) = ((n>>5)*64 + (k>>3))*256 + (n&31)*8 + (k&7)
// ---------------------------------------------------------------------------
__global__ __launch_bounds__(256) void k_prep_w(const float* __restrict__ W,
                                                _Float16* __restrict__ wt_hi,
                                                _Float16* __restrict__ wt_lo) {
    const int idx = blockIdx.x * 256 + threadIdx.x;  // 131072
    const int n = idx & 255, k = idx >> 8;
    const float v = W[(size_t)k * DD + n];
    const _Float16 hi = (_Float16)v;
    const _Float16 lo = (_Float16)(v - (float)hi);
    const int off = (((n >> 5) * 64 + (k >> 3)) << 8) + ((n & 31) << 3) + (k & 7);
    wt_hi[off] = hi;
    wt_lo[off] = lo;
}

// ---------------------------------------------------------------------------
// K1: h = x@W + b via split-fp16 MFMA (hi*hi + hi*lo + lo*hi). Verified R4.
// ---------------------------------------------------------------------------
__global__ __launch_bounds__(256) void k_gemm1(const float* __restrict__ x,
                                               const _Float16* __restrict__ wt_hi,
                                               const _Float16* __restrict__ wt_lo,
                                               const float* __restrict__ b,
                                               float* __restrict__ h) {
    __shared__ _Float16 sH[64 * 64];  // tiled [mblk2][kg8][32][8]
    __shared__ _Float16 sL[64 * 64];
    const int tid = threadIdx.x, lane = tid & 63, w = tid >> 6;
    const int wy = w >> 1, wx = w & 1;
    const int m0 = blockIdx.x * 64;

    float16v acc[4];
#pragma unroll
    for (int j = 0; j < 4; ++j) acc[j] = (float16v)(0.0f);

    for (int kb = 0; kb < ZC; kb += 64) {
        __syncthreads();
        {
            const int m = tid & 63;
            const int kp = tid >> 6;  // 0..3
#pragma unroll
            for (int i2 = 0; i2 < 2; ++i2) {
                const int kg = kp * 2 + i2;
                const float* src = x + (size_t)(m0 + m) * ZC + kb + kg * 8;
                float4v v0 = *(const float4v*)src;
                float4v v1 = *(const float4v*)(src + 4);
                half8 hi, lo;
                float vv[8] = {v0.x, v0.y, v0.z, v0.w, v1.x, v1.y, v1.z, v1.w};
#pragma unroll
                for (int j = 0; j < 8; ++j) {
                    hi[j] = (_Float16)vv[j];
                    lo[j] = (_Float16)(vv[j] - (float)hi[j]);
                }
                const int off = (((m >> 5) * 8 + kg) << 8) + ((m & 31) << 3);
                *(half8*)&sH[off] = hi;
                *(half8*)&sL[off] = lo;
            }
        }
        __syncthreads();
#pragma unroll
        for (int s = 0; s < 4; ++s) {
            const int S = (kb >> 4) + s;  // global k-step
            half8 ah = *(const half8*)&sH[((wy * 8 + 2 * s) << 8) + lane * 8];
            half8 al = *(const half8*)&sL[((wy * 8 + 2 * s) << 8) + lane * 8];
#pragma unroll
            for (int nf = 0; nf < 4; ++nf) {
                const int nblk = wx * 4 + nf;
                const size_t boff = ((size_t)(nblk * 64 + 2 * S) << 8) + lane * 8;
                half8 bh = *(const half8*)&wt_hi[boff];
                half8 bl = *(const half8*)&wt_lo[boff];
                acc[nf] = __builtin_amdgcn_mfma_f32_32x32x16_f16(ah, bh, acc[nf], 0, 0, 0);
                acc[nf] = __builtin_amdgcn_mfma_f32_32x32x16_f16(ah, bl, acc[nf], 0, 0, 0);
                acc[nf] = __builtin_amdgcn_mfma_f32_32x32x16_f16(al, bh, acc[nf], 0, 0, 0);
            }
        }
    }
    // Epilogue: C layout col=lane&31, row=(r&3)+8*(r>>2)+4*(lane>>5)
#pragma unroll
    for (int nf = 0; nf < 4; ++nf) {
        const int col = wx * 128 + nf * 32 + (lane & 31);
        const float bias = b[col];
#pragma unroll
        for (int r = 0; r < 16; ++r) {
            const int row = m0 + wy * 32 + (r & 3) + 8 * (r >> 2) + 4 * (lane >> 5);
            h[(size_t)row * DD + col] = acc[nf][r] + bias;
        }
    }
}

// ---------------------------------------------------------------------------
// Prep h: fp16 MFMA-tiled copy + row squared-norms (folds old k_rownorm).
// ht off(row,k) = ((row>>5)*32 + (k>>3))*256 + (row&31)*8 + (k&7)
// ---------------------------------------------------------------------------
__global__ __launch_bounds__(256) void k_prep_h(const float* __restrict__ h,
                                                _Float16* __restrict__ ht,
                                                float* __restrict__ hh) {
    const int lane = threadIdx.x & 63, w = threadIdx.x >> 6;
    const int row = blockIdx.x * 4 + w;
    float4v v = *(const float4v*)&h[(size_t)row * DD + lane * 4];
    half2v p0, p1;
    p0.x = (_Float16)v.x; p0.y = (_Float16)v.y;
    p1.x = (_Float16)v.z; p1.y = (_Float16)v.w;
    const size_t off = ((size_t)((row >> 5) * 32 + (lane >> 1)) << 8) +
                       ((row & 31) << 3) + ((lane & 1) << 2);
    *(half2v*)&ht[off] = p0;
    *(half2v*)&ht[off + 2] = p1;
    float s = v.x * v.x + v.y * v.y + v.z * v.z + v.w * v.w;
#pragma unroll
    for (int o = 32; o; o >>= 1) s += __shfl_down(s, o);
    if (lane == 0) hh[row] = s;
}

// ---------------------------------------------------------------------------
// Prep codebook: fp16 MFMA-tiled copy + squared norms + zero loss buckets.
// ---------------------------------------------------------------------------
__global__ __launch_bounds__(256) void k_prep_cb(const float* __restrict__ cb,
                                                 _Float16* __restrict__ cbt,
                                                 float* __restrict__ ee,
                                                 float* __restrict__ loss_part) {
    if (blockIdx.x == 0) loss_part[threadIdx.x] = 0.0f;
    const int lane = threadIdx.x & 63, w = threadIdx.x >> 6;
    const int code = blockIdx.x * 4 + w;
    float4v v = *(const float4v*)&cb[(size_t)code * DD + lane * 4];
    half2v p0, p1;
    p0.x = (_Float16)v.x; p0.y = (_Float16)v.y;
    p1.x = (_Float16)v.z; p1.y = (_Float16)v.w;
    const size_t off = ((size_t)((code >> 5) * 32 + (lane >> 1)) << 8) +
                       ((code & 31) << 3) + ((lane & 1) << 2);
    *(half2v*)&cbt[off] = p0;
    *(half2v*)&cbt[off + 2] = p1;
    float s = v.x * v.x + v.y * v.y + v.z * v.z + v.w * v.w;
#pragma unroll
    for (int o = 32; o; o >>= 1) s += __shfl_down(s, o);
    if (lane == 0) ee[code] = s;
}

// ---------------------------------------------------------------------------
// Phase 1 distance kernel — R5: joint-nj FOUR-chain compute.
//
// R0-R3: three different schedules all land at 131-133us, MfmaUtil ~51%;
// effective 15.7 cyc/MFMA ~= 2x the 8.07-cyc throughput. Theory: dependent
// issue latency ~32 cyc on the accumulator chain; 2 chains -> same-chain
// distance 16 cyc -> issue pinned at half rate, schedule-invariant.
// Fix: compute BOTH 32-row njs simultaneously. Per k-substep s: read
// bf0=B(nj0,s), bf1=B(nj1,s); issue 4 MFMAs into 4 true accumulators
// A00,A01,A10,A11 (acc[nj][mi]) -> same-chain distance 4 MFMAs = 32 cyc.
// No merge adds (unlike R4's parity-split); ext-fold lands once per chain;
// one combined epilogue. ~+64 VGPR vs R3 (acc 64 + afr 64 + frags).
//
// Staging: counted vmcnt (R3-verified). Stores per half-stage unchanged
// (2 njs x 4 = 8), so counts carry over: steady-state queue at iter-t wait
// = [8 loads-t][8 stores-(t-1)][8 loads-(t+1)] -> vmcnt(16). t=0:
// [8 loads-0][8 loads-1] -> vmcnt(8). Tail t=15: [8 loads][8 stores] ->
// vmcnt(8).
//
// A-frag k-mapping: lane L holds k = (L>>5)*8 + j  =>  byte addr must use
// lane*8 = csel*256 + lw*8 halves (R5 bug: csel*512 read the wrong k-slice).
// ee folded as a 17th k-substep: A_ext[c][0]=ee[c], B_ext[r][0]=-0.5,
// so s = ee - 2*dot = -2*acc.
// ---------------------------------------------------------------------------
__global__ __launch_bounds__(256, 2) void k_dist(const _Float16* __restrict__ ht,
                                                 const _Float16* __restrict__ cbt,
                                                 const float* __restrict__ ee,
                                                 _Float16* __restrict__ smin) {
    __shared__ _Float16 sB[2][64 * 256];  // 2 x 32 KB, tiled [rowblk2][kg32][32][8]
    const int tid = threadIdx.x, lane = tid & 63, w = tid >> 6;
    const int lw = lane & 31, csel = lane >> 5;
    const int bx = blockIdx.x;  // 256-code split (32)
    const int by = blockIdx.y;  // 1024-row split (32)

    // Load A: 2 mfrags x 16 k-substeps, each half8 (codes in lanes&31).
    half8 afr[2][16];
    const size_t lo = (size_t)lane * 8;  // = csel*256 + lw*8 (kg = 2s+csel)
#pragma unroll
    for (int mi = 0; mi < 2; ++mi) {
        const _Float16* base = cbt + (size_t)(bx * 8 + w * 2 + mi) * 8192;
#pragma unroll
        for (int s = 0; s < 16; ++s)
            afr[mi][s] = *(const half8*)(base + s * 512 + lo);
    }
    // ee-folding ext frags
    half8 aext[2], bext;
#pragma unroll
    for (int j = 0; j < 8; ++j) bext[j] = (_Float16)0.f;
    if (csel == 0) bext[0] = (_Float16)(-0.5f);
#pragma unroll
    for (int mi = 0; mi < 2; ++mi) {
        const float e = ee[bx * 256 + w * 64 + mi * 32 + lw];
#pragma unroll
        for (int j = 0; j < 8; ++j) aext[mi][j] = (_Float16)0.f;
        if (csel == 0) aext[mi][0] = (_Float16)e;
    }

    // Staging: half-stage t = 64 rows = 32 KB; wave copies its 8 KB quarter
    // via 8 global_load_lds dwordx4 (wave-uniform LDS base + lane*16).
    const _Float16* hbase = ht + (size_t)by * 1024 * 256 + (size_t)w * 4096 + lane * 8;
#define STAGE_HS(buf, t)                                                       \
    do {                                                                       \
        const _Float16* g_ = hbase + (size_t)(t) * 16384;                      \
        char* l_ = (char*)&sB[(buf)][0] + w * 8192;                            \
        _Pragma("unroll")                                                      \
        for (int i_ = 0; i_ < 8; ++i_)                                         \
            ASYNC_CP16(g_ + i_ * 512, l_ + i_ * 1024);                         \
    } while (0)

    // B-fragment read: nj in {0,1}, s in {0..15}.
#define LDB(sb_, nj_, s_)                                                      \
    (*(const half8*)&(sb_)[(size_t)((((nj_) * 32) + 2 * (s_) + csel) << 8) + lw * 8])

    // Per-nj epilogue from two accumulators.
#define EPI(accA, accB, nj_)                                                   \
    do {                                                                       \
        float g0a = (accA)[0], g1a = (accA)[8];                                \
        float g0b = (accB)[0], g1b = (accB)[8];                                \
        _Pragma("unroll")                                                      \
        for (int r = 1; r < 8; ++r) {                                          \
            g0a = fmaxf(g0a, (accA)[r]);  g1a = fmaxf(g1a, (accA)[8 + r]);     \
            g0b = fmaxf(g0b, (accB)[r]);  g1b = fmaxf(g1b, (accB)[8 + r]);     \
        }                                                                      \
        g0a = fmaxf(g0a, __shfl_xor(g0a, 32));                                 \
        g1a = fmaxf(g1a, __shfl_xor(g1a, 32));                                 \
        g0b = fmaxf(g0b, __shfl_xor(g0b, 32));                                 \
        g1b = fmaxf(g1b, __shfl_xor(g1b, 32));                                 \
        if (lane < 32) {                                                       \
            const int row_ = r0_ + (nj_) * 32 + lane;                          \
            const int gb_ = bx * 16 + w * 4;                                   \
            smin[(size_t)(gb_ + 0) * M_TOT + row_] = (_Float16)(-2.f * g0a);   \
            smin[(size_t)(gb_ + 1) * M_TOT + row_] = (_Float16)(-2.f * g1a);   \
            smin[(size_t)(gb_ + 2) * M_TOT + row_] = (_Float16)(-2.f * g0b);   \
            smin[(size_t)(gb_ + 3) * M_TOT + row_] = (_Float16)(-2.f * g1b);   \
        }                                                                      \
    } while (0)

    // Compute one half-stage (64 rows): both njs jointly, 4 MFMA chains.
#define COMPUTE_HS(buf, t)                                                     \
    do {                                                                       \
        const int r0_ = by * 1024 + (t) * 64;                                  \
        const _Float16* sb_ = &sB[(buf)][0];                                   \
        float16v A00 = (float16v)(0.f), A01 = (float16v)(0.f);                 \
        float16v A10 = (float16v)(0.f), A11 = (float16v)(0.f);                 \
        __builtin_amdgcn_s_setprio(1);                                         \
        _Pragma("unroll")                                                      \
        for (int s = 0; s < 16; ++s) {                                         \
            half8 bf0 = LDB(sb_, 0, s);                                        \
            half8 bf1 = LDB(sb_, 1, s);                                        \
            A00 = __builtin_amdgcn_mfma_f32_32x32x16_f16(afr[0][s], bf0, A00, 0, 0, 0); \
            A01 = __builtin_amdgcn_mfma_f32_32x32x16_f16(afr[1][s], bf0, A01, 0, 0, 0); \
            A10 = __builtin_amdgcn_mfma_f32_32x32x16_f16(afr[0][s], bf1, A10, 0, 0, 0); \
            A11 = __builtin_amdgcn_mfma_f32_32x32x16_f16(afr[1][s], bf1, A11, 0, 0, 0); \
        }                                                                      \
        A00 = __builtin_amdgcn_mfma_f32_32x32x16_f16(aext[0], bext, A00, 0, 0, 0); \
        A01 = __builtin_amdgcn_mfma_f32_32x32x16_f16(aext[1], bext, A01, 0, 0, 0); \
        A10 = __builtin_amdgcn_mfma_f32_32x32x16_f16(aext[0], bext, A10, 0, 0, 0); \
        A11 = __builtin_amdgcn_mfma_f32_32x32x16_f16(aext[1], bext, A11, 0, 0, 0); \
        __builtin_amdgcn_s_setprio(0);                                         \
        EPI(A00, A01, 0);                                                      \
        EPI(A10, A11, 1);                                                      \
    } while (0)

    // Prologue: stage half-stages 0 and 1.
    STAGE_HS(0, 0);
    STAGE_HS(1, 1);
    // t=0: queue = [8 loads-0][8 loads-1] -> vmcnt(8) retires loads-0.
    asm volatile("s_waitcnt vmcnt(8)" ::: "memory");
    __builtin_amdgcn_s_barrier();
    __builtin_amdgcn_sched_barrier(0);
    COMPUTE_HS(0, 0);
    __builtin_amdgcn_sched_barrier(0);
    __builtin_amdgcn_s_barrier();

    // Steady state t=1..14: queue at wait =
    // [8 loads-t][8 stores-(t-1)][8 loads-(t+1)] -> vmcnt(16).
#pragma unroll 1
    for (int t = 1; t < 15; ++t) {
        const int cur = t & 1;
        STAGE_HS(cur ^ 1, t + 1);
        asm volatile("s_waitcnt vmcnt(16)" ::: "memory");  // loads-t landed
        __builtin_amdgcn_s_barrier();
        __builtin_amdgcn_sched_barrier(0);
        COMPUTE_HS(cur, t);
        __builtin_amdgcn_sched_barrier(0);
        __builtin_amdgcn_s_barrier();
    }
    // Tail t=15: queue = [8 loads-15][8 stores-14] -> vmcnt(8).
    asm volatile("s_waitcnt vmcnt(8)" ::: "memory");
    __builtin_amdgcn_s_barrier();
    __builtin_amdgcn_sched_barrier(0);
    COMPUTE_HS(1, 15);

#undef STAGE_HS
#undef COMPUTE_HS
#undef LDB
#undef EPI
}

// ---------------------------------------------------------------------------
// Phase 2: wave-per-row (verified R4). LDS-transpose 64-row slab of smin_T,
// margin-filter granules, exact fp32 rescore ((hh+ee)-2*dot, lowest-index
// tie-break), gather zq, write out, bucketized loss.
// ---------------------------------------------------------------------------
__global__ __launch_bounds__(256, 2) void k_select(const float* __restrict__ h,
                                                   const float* __restrict__ cb,
                                                   const float* __restrict__ hh,
                                                   const float* __restrict__ ee,
                                                   const _Float16* __restrict__ smin,
                                                   float* __restrict__ out,
                                                   float* __restrict__ loss_part) {
    __shared__ _Float16 sS[64][512];  // [row][granule] = 64 KB
    const int t = threadIdx.x, lane = t & 63, w = t >> 6;
    const int r0 = blockIdx.x * 64;

    for (int gi = t; gi < NGRAN; gi += 256) {
        const _Float16* src = smin + (size_t)gi * M_TOT + r0;
#pragma unroll
        for (int c = 0; c < 8; ++c) {
            half8 v = *(const half8*)(src + c * 8);
#pragma unroll
            for (int j = 0; j < 8; ++j) sS[c * 8 + j][gi] = v[j];
        }
    }
    __syncthreads();

    float lossacc = 0.0f;
    for (int i = 0; i < 16; ++i) {
        const int row = r0 + w * 16 + i;
        float4v hv = *(const float4v*)&h[(size_t)row * DD + lane * 4];
        half8 sm = *(const half8*)&sS[w * 16 + i][lane * 8];
        float vmin = 1e30f;
        float sv[8];
#pragma unroll
        for (int j = 0; j < 8; ++j) {
            sv[j] = (float)sm[j];
            vmin = fminf(vmin, sv[j]);
        }
        float m2 = vmin;
#pragma unroll
        for (int o = 32; o; o >>= 1) m2 = fminf(m2, __shfl_xor(m2, o));
        const float thr = m2 + MARGIN;
        unsigned flags = 0;
#pragma unroll
        for (int j = 0; j < 8; ++j)
            if (sv[j] <= thr) flags |= (1u << j);

        unsigned long long act = __ballot(flags != 0);
        unsigned long long bestk = ~0ull;
        const float hhv = hh[row];
        while (act) {
            const int ln = __ffsll((long long)act) - 1;
            act &= act - 1;
            unsigned fl = (unsigned)__shfl((int)flags, ln);
            while (fl) {
                const int j = __ffs(fl) - 1;
                fl &= fl - 1;
                const int g = ln * 8 + j;
#pragma unroll
                for (int c = 0; c < 16; ++c) {
                    const int code = g * 16 + c;
                    float4v cv = *(const float4v*)&cb[(size_t)code * DD + lane * 4];
                    float s = hv.x * cv.x + hv.y * cv.y + hv.z * cv.z + hv.w * cv.w;
#pragma unroll
                    for (int o = 32; o; o >>= 1) s += __shfl_xor(s, o);
                    const float d = (hhv + ee[code]) - 2.0f * s;  // reference formula
                    const unsigned bts = __float_as_uint(d);
                    const unsigned mb =
                        bts ^ (unsigned)(((int)bts >> 31) | 0x80000000);
                    const unsigned long long key =
                        ((unsigned long long)mb << 32) | (unsigned)code;
                    if (key < bestk) bestk = key;
                }
            }
        }
        const unsigned best = (unsigned)(bestk & 0xffffffffull);
        float4v cv = *(const float4v*)&cb[(size_t)best * DD + lane * 4];
        *(float4v*)&out[(size_t)row * DD + lane * 4] = cv;
        const float dx = cv.x - hv.x, dy = cv.y - hv.y;
        const float dz = cv.z - hv.z, dw = cv.w - hv.w;
        lossacc += dx * dx + dy * dy + dz * dz + dw * dw;
    }
#pragma unroll
    for (int o = 32; o; o >>= 1) lossacc += __shfl_xor(lossacc, o);
    if (lane == 0)
        atomicAdd(&loss_part[(blockIdx.x * 4 + w) & (NBUCKET - 1)], lossacc);
}

__global__ __launch_bounds__(256) void k_final(const float* __restrict__ loss_part,
                                               float* __restrict__ out) {
    const int t = threadIdx.x;
    float s = loss_part[t];
#pragma unroll
    for (int off = 32; off; off >>= 1) s += __shfl_down(s, off);
    __shared__ float wsum[4];
    if ((t & 63) == 0) wsum[t >> 6] = s;
    __syncthreads();
    if (t == 0)
        out[0] = 1.25f * ((wsum[0] + wsum[1]) + (wsum[2] + wsum[3]))
                 / (float)(M_TOT * DD);  // BETA*mean + mean
}

// ---------------------------------------------------------------------------
extern "C" void kernel_launch(void* const* d_in, const int* in_sizes, int n_in,
                              void* d_out, int out_size, void* d_ws, size_t ws_size,
                              hipStream_t stream) {
    const float* x  = (const float*)d_in[0];
    const float* W  = (const float*)d_in[1];
    const float* b  = (const float*)d_in[2];
    const float* cb = (const float*)d_in[3];
    float* out = (float*)d_out;

    char* ws = (char*)d_ws;
    float* h        = (float*)(ws + OFF_H);
    _Float16* ht    = (_Float16*)(ws + OFF_HT);
    _Float16* cbt   = (_Float16*)(ws + OFF_CBT);
    _Float16* wt_hi = (_Float16*)(ws + OFF_WTH);
    _Float16* wt_lo = (_Float16*)(ws + OFF_WTL);
    float* hh       = (float*)(ws + OFF_HH);
    float* ee       = (float*)(ws + OFF_EE);
    _Float16* smin  = (_Float16*)(ws + OFF_SMIN);
    float* loss_part = (float*)(ws + OFF_LOSSP);

    hipLaunchKernelGGL(k_prep_w, dim3(512), dim3(256), 0, stream, W, wt_hi, wt_lo);
    hipLaunchKernelGGL(k_prep_cb, dim3(KCODES / 4), dim3(256), 0, stream,
                       cb, cbt, ee, loss_part);
    hipLaunchKernelGGL(k_gemm1, dim3(M_TOT / 64), dim3(256), 0, stream,
                       x, wt_hi, wt_lo, b, h);
    hipLaunchKernelGGL(k_prep_h, dim3(M_TOT / 4), dim3(256), 0, stream,
                       h, ht, hh);
    hipLaunchKernelGGL(k_dist, dim3(KCODES / 256, M_TOT / 1024), dim3(256),
                       0, stream, ht, cbt, ee, smin);
    hipLaunchKernelGGL(k_select, dim3(M_TOT / 64), dim3(256), 0, stream,
                       h, cb, hh, ee, smin, out, loss_part);
    hipLaunchKernelGGL(k_final, dim3(1), dim3(256), 0, stream,
                       loss_part, out + (size_t)M_TOT * DD);
}

// Round 7
// 354.447 us; speedup vs baseline: 1.0620x; 1.0359x over previous
//
#include <hip/hip_runtime.h>
#include <stdint.h>

// Problem constants (B=8, T=4096, Zc=512, D=256, K=8192)
#define M_TOT 32768
#define ZC 512
#define DD 256
#define KCODES 8192
#define NGRAN 512            // KCODES / 16 codes per granule
#define MARGIN 0.15f         // >2x hard fp16-error bound (validated R2/R3/R4)
#define NBUCKET 256

typedef _Float16 half8   __attribute__((ext_vector_type(8)));
typedef _Float16 half2v  __attribute__((ext_vector_type(2)));
typedef float    float4v __attribute__((ext_vector_type(4)));
typedef float    float16v __attribute__((ext_vector_type(16)));

// Workspace layout (bytes). wt_hi/wt_lo overlap smin: prep/gemm1 finish
// before k_dist writes smin (stream-ordered, every launch identical).
#define OFF_H     0ull                  // h fp32: 32 MB
#define OFF_HT    33554432ull           // ht fp16 tiled: 16 MB
#define OFF_CBT   50331648ull           // cbt fp16 tiled: 4 MB
#define OFF_HH    54525952ull           // hh: 128 KB
#define OFF_EE    54657024ull           // ee: 32 KB
#define OFF_LOSSP 54689792ull           // loss buckets: 1 KB
#define OFF_SMIN  54691840ull           // smin_T fp16 [NGRAN][M_TOT]: 32 MB
#define OFF_WTH   OFF_SMIN              // Wt_hi fp16 tiled: 512 KB (overlap)
#define OFF_WTL   (OFF_SMIN + 524288ull) // Wt_lo fp16 tiled: 512 KB (overlap)

// async global->LDS, 16B per lane, LDS dst = wave-uniform base + lane*16
#define ASYNC_CP16(gp, lp)                                                     \
  __builtin_amdgcn_global_load_lds(                                            \
      (const __attribute__((address_space(1))) void*)(gp),                     \
      (__attribute__((address_space(3))) void*)(lp), 16, 0, 0)

// ---------------------------------------------------------------------------
// Merged prep (R7): W split-fp16 tiling (blocks 0..511) + codebook fp16
// tiling / norms / loss-bucket zero (blocks 512..2559). One launch less.
// W tiled:  off(n,k) = ((n>>5)*64 + (k>>3))*256 + (n&31)*8 + (k&7)
// cb tiled: off(code,k) = ((code>>5)*32 + (k>>3))*256 + (code&31)*8 + (k&7)
// ---------------------------------------------------------------------------
__global__ __launch_bounds__(256) void k_prep(const float* __restrict__ W,
                                              const float* __restrict__ cb,
                                              _Float16* __restrict__ wt_hi,
                                              _Float16* __restrict__ wt_lo,
                                              _Float16* __restrict__ cbt,
                                              float* __restrict__ ee,
                                              float* __restrict__ loss_part) {
    const int bx = blockIdx.x;
    if (bx < 512) {
        const int idx = bx * 256 + threadIdx.x;  // 131072
        const int n = idx & 255, k = idx >> 8;
        const float v = W[(size_t)k * DD + n];
        const _Float16 hi = (_Float16)v;
        const _Float16 lo = (_Float16)(v - (float)hi);
        const int off = (((n >> 5) * 64 + (k >> 3)) << 8) + ((n & 31) << 3) + (k & 7);
        wt_hi[off] = hi;
        wt_lo[off] = lo;
        return;
    }
    if (bx == 512) loss_part[threadIdx.x] = 0.0f;
    const int lane = threadIdx.x & 63, w = threadIdx.x >> 6;
    const int code = (bx - 512) * 4 + w;
    float4v v = *(const float4v*)&cb[(size_t)code * DD + lane * 4];
    half2v p0, p1;
    p0.x = (_Float16)v.x; p0.y = (_Float16)v.y;
    p1.x = (_Float16)v.z; p1.y = (_Float16)v.w;
    const size_t off = ((size_t)((code >> 5) * 32 + (lane >> 1)) << 8) +
                       ((code & 31) << 3) + ((lane & 1) << 2);
    *(half2v*)&cbt[off] = p0;
    *(half2v*)&cbt[off + 2] = p1;
    float s = v.x * v.x + v.y * v.y + v.z * v.z + v.w * v.w;
#pragma unroll
    for (int o = 32; o; o >>= 1) s += __shfl_down(s, o);
    if (lane == 0) ee[code] = s;
}

// ---------------------------------------------------------------------------
// K1 (R7-fused): h = x@W + b via split-fp16 MFMA (verified R4), PLUS fused
// k_prep_h: epilogue stages fp32 acc+bias into an XOR-swizzled 32KB LDS
// buffer, writes h fp32 (as before), computes per-row sumsq (hh) via lane
// butterfly + LDS combine, then emits MFMA-tiled fp16 ht with coalesced
// half8 stores. Removes the old 32MB-read/16MB-write k_prep_h kernel.
// ht values bit-identical (same fp32 source -> same fp16 rounding). hh
// summation order differs from old kernel but hh enters d as a per-row
// constant (monotone add) -> argmin ordering unchanged.
// sT swizzle: idx = row*256 + (col ^ ((row&7)<<3)) — keeps 8-half groups
// contiguous (xor bits >=3) and spreads the read-phase banks.
// ---------------------------------------------------------------------------
__global__ __launch_bounds__(256) void k_gemm1(const float* __restrict__ x,
                                               const _Float16* __restrict__ wt_hi,
                                               const _Float16* __restrict__ wt_lo,
                                               const float* __restrict__ b,
                                               float* __restrict__ h,
                                               _Float16* __restrict__ ht,
                                               float* __restrict__ hh) {
    __shared__ _Float16 sH[64 * 64];  // tiled [mblk2][kg8][32][8]
    __shared__ _Float16 sL[64 * 64];
    __shared__ _Float16 sT[64 * 256]; // 32KB fp16 transpose staging (swizzled)
    __shared__ float sHH[64];
    const int tid = threadIdx.x, lane = tid & 63, w = tid >> 6;
    const int lw = lane & 31, csel = lane >> 5;
    const int wy = w >> 1, wx = w & 1;
    const int m0 = blockIdx.x * 64;

    float16v acc[4];
#pragma unroll
    for (int j = 0; j < 4; ++j) acc[j] = (float16v)(0.0f);

    for (int kb = 0; kb < ZC; kb += 64) {
        __syncthreads();
        {
            const int m = tid & 63;
            const int kp = tid >> 6;  // 0..3
#pragma unroll
            for (int i2 = 0; i2 < 2; ++i2) {
                const int kg = kp * 2 + i2;
                const float* src = x + (size_t)(m0 + m) * ZC + kb + kg * 8;
                float4v v0 = *(const float4v*)src;
                float4v v1 = *(const float4v*)(src + 4);
                half8 hi, lo;
                float vv[8] = {v0.x, v0.y, v0.z, v0.w, v1.x, v1.y, v1.z, v1.w};
#pragma unroll
                for (int j = 0; j < 8; ++j) {
                    hi[j] = (_Float16)vv[j];
                    lo[j] = (_Float16)(vv[j] - (float)hi[j]);
                }
                const int off = (((m >> 5) * 8 + kg) << 8) + ((m & 31) << 3);
                *(half8*)&sH[off] = hi;
                *(half8*)&sL[off] = lo;
            }
        }
        __syncthreads();
#pragma unroll
        for (int s = 0; s < 4; ++s) {
            const int S = (kb >> 4) + s;  // global k-step
            half8 ah = *(const half8*)&sH[((wy * 8 + 2 * s) << 8) + lane * 8];
            half8 al = *(const half8*)&sL[((wy * 8 + 2 * s) << 8) + lane * 8];
#pragma unroll
            for (int nf = 0; nf < 4; ++nf) {
                const int nblk = wx * 4 + nf;
                const size_t boff = ((size_t)(nblk * 64 + 2 * S) << 8) + lane * 8;
                half8 bh = *(const half8*)&wt_hi[boff];
                half8 bl = *(const half8*)&wt_lo[boff];
                acc[nf] = __builtin_amdgcn_mfma_f32_32x32x16_f16(ah, bh, acc[nf], 0, 0, 0);
                acc[nf] = __builtin_amdgcn_mfma_f32_32x32x16_f16(ah, bl, acc[nf], 0, 0, 0);
                acc[nf] = __builtin_amdgcn_mfma_f32_32x32x16_f16(al, bh, acc[nf], 0, 0, 0);
            }
        }
    }
    // ---- Fused epilogue. C layout: col=lane&31(+nf,wx), row=(r&3)+8*(r>>2)+4*csel.
    float bias[4];
#pragma unroll
    for (int nf = 0; nf < 4; ++nf) bias[nf] = b[wx * 128 + nf * 32 + lw];

    float pr[16];
    __syncthreads();  // sH/sL reads done; sT may alias nothing, but order waves
#pragma unroll
    for (int r = 0; r < 16; ++r) {
        const int row = wy * 32 + (r & 3) + 8 * (r >> 2) + 4 * csel;  // 0..63
        float p = 0.f;
#pragma unroll
        for (int nf = 0; nf < 4; ++nf) {
            const int col = wx * 128 + nf * 32 + lw;
            const float v = acc[nf][r] + bias[nf];
            h[(size_t)(m0 + row) * DD + col] = v;
            sT[row * 256 + (col ^ ((row & 7) << 3))] = (_Float16)v;
            p += v * v;
        }
#pragma unroll
        for (int o = 16; o; o >>= 1) p += __shfl_xor(p, o);  // sum over 32 lw lanes
        pr[r] = p;
        if (wx == 0 && lw == 0) sHH[row] = p;  // this wave's 128 cols
    }
    __syncthreads();
    if (wx == 1 && lw == 0) {
#pragma unroll
        for (int r = 0; r < 16; ++r) {
            const int row = wy * 32 + (r & 3) + 8 * (r >> 2) + 4 * csel;
            sHH[row] += pr[r];  // other 128 cols (rows disjoint across waves)
        }
    }
    __syncthreads();
    // ht: 64-row slab = 32KB contiguous at ht + m0*256. j = chunk*32+rr;
    // chunk c = rb*32+kg; src row = rb*32+rr; dst = ht + m0*256 + j*8.
#pragma unroll
    for (int i = 0; i < 8; ++i) {
        const int j = tid + i * 256;
        const int c = j >> 5, rr = j & 31;
        const int row = (c >> 5) * 32 + rr, kg = c & 31;
        half8 v = *(const half8*)&sT[row * 256 + ((kg * 8) ^ ((row & 7) << 3))];
        *(half8*)&ht[(size_t)m0 * 256 + (size_t)j * 8] = v;
    }
    if (tid < 64) hh[m0 + tid] = sHH[tid];
}

// ---------------------------------------------------------------------------
// Phase 1 distance kernel — R6 (frozen): joint-nj FOUR-chain compute.
// R0-R6 history: counted-vmcnt dbuf / c=4 reuse / chunk-pipelining all
// neutral at ~51% MfmaUtil; 4-chain joint-nj = 126us @ 54.8% — the
// design's plateau (sum-of-pipes: MFMA 69 + LDS 41 + VALU 26 ~= wall).
// Reuse up needs regs (kills occupancy, R2); overlap up needs waves
// (register-bound at 2/SIMD). Frozen.
//
// Staging: counted vmcnt. Steady-state queue at iter-t wait:
// [8 loads-t][8 stores-(t-1)][8 loads-(t+1)] -> vmcnt(16). t=0: vmcnt(8).
// Tail t=15: vmcnt(8).
// A-frag k-mapping: lane L holds k = (L>>5)*8 + j => byte addr lane*8.
// ee folded as 17th k-substep: s = ee - 2*dot = -2*acc.
// ---------------------------------------------------------------------------
__global__ __launch_bounds__(256, 2) void k_dist(const _Float16* __restrict__ ht,
                                                 const _Float16* __restrict__ cbt,
                                                 const float* __restrict__ ee,
                                                 _Float16* __restrict__ smin) {
    __shared__ _Float16 sB[2][64 * 256];  // 2 x 32 KB, tiled [rowblk2][kg32][32][8]
    const int tid = threadIdx.x, lane = tid & 63, w = tid >> 6;
    const int lw = lane & 31, csel = lane >> 5;
    const int bx = blockIdx.x;  // 256-code split (32)
    const int by = blockIdx.y;  // 1024-row split (32)

    // Load A: 2 mfrags x 16 k-substeps, each half8 (codes in lanes&31).
    half8 afr[2][16];
    const size_t lo = (size_t)lane * 8;  // = csel*256 + lw*8 (kg = 2s+csel)
#pragma unroll
    for (int mi = 0; mi < 2; ++mi) {
        const _Float16* base = cbt + (size_t)(bx * 8 + w * 2 + mi) * 8192;
#pragma unroll
        for (int s = 0; s < 16; ++s)
            afr[mi][s] = *(const half8*)(base + s * 512 + lo);
    }
    // ee-folding ext frags
    half8 aext[2], bext;
#pragma unroll
    for (int j = 0; j < 8; ++j) bext[j] = (_Float16)0.f;
    if (csel == 0) bext[0] = (_Float16)(-0.5f);
#pragma unroll
    for (int mi = 0; mi < 2; ++mi) {
        const float e = ee[bx * 256 + w * 64 + mi * 32 + lw];
#pragma unroll
        for (int j = 0; j < 8; ++j) aext[mi][j] = (_Float16)0.f;
        if (csel == 0) aext[mi][0] = (_Float16)e;
    }

    // Staging: half-stage t = 64 rows = 32 KB; wave copies its 8 KB quarter
    // via 8 global_load_lds dwordx4 (wave-uniform LDS base + lane*16).
    const _Float16* hbase = ht + (size_t)by * 1024 * 256 + (size_t)w * 4096 + lane * 8;
#define STAGE_HS(buf, t)                                                       \
    do {                                                                       \
        const _Float16* g_ = hbase + (size_t)(t) * 16384;                      \
        char* l_ = (char*)&sB[(buf)][0] + w * 8192;                            \
        _Pragma("unroll")                                                      \
        for (int i_ = 0; i_ < 8; ++i_)                                         \
            ASYNC_CP16(g_ + i_ * 512, l_ + i_ * 1024);                         \
    } while (0)

    // B-fragment read: nj in {0,1}, s in {0..15}.
#define LDB(sb_, nj_, s_)                                                      \
    (*(const half8*)&(sb_)[(size_t)((((nj_) * 32) + 2 * (s_) + csel) << 8) + lw * 8])

    // Per-nj epilogue from two accumulators.
#define EPI(accA, accB, nj_)                                                   \
    do {                                                                       \
        float g0a = (accA)[0], g1a = (accA)[8];                                \
        float g0b = (accB)[0], g1b = (accB)[8];                                \
        _Pragma("unroll")                                                      \
        for (int r = 1; r < 8; ++r) {                                          \
            g0a = fmaxf(g0a, (accA)[r]);  g1a = fmaxf(g1a, (accA)[8 + r]);     \
            g0b = fmaxf(g0b, (accB)[r]);  g1b = fmaxf(g1b, (accB)[8 + r]);     \
        }                                                                      \
        g0a = fmaxf(g0a, __shfl_xor(g0a, 32));                                 \
        g1a = fmaxf(g1a, __shfl_xor(g1a, 32));                                 \
        g0b = fmaxf(g0b, __shfl_xor(g0b, 32));                                 \
        g1b = fmaxf(g1b, __shfl_xor(g1b, 32));                                 \
        if (lane < 32) {                                                       \
            const int row_ = r0_ + (nj_) * 32 + lane;                          \
            const int gb_ = bx * 16 + w * 4;                                   \
            smin[(size_t)(gb_ + 0) * M_TOT + row_] = (_Float16)(-2.f * g0a);   \
            smin[(size_t)(gb_ + 1) * M_TOT + row_] = (_Float16)(-2.f * g1a);   \
            smin[(size_t)(gb_ + 2) * M_TOT + row_] = (_Float16)(-2.f * g0b);   \
            smin[(size_t)(gb_ + 3) * M_TOT + row_] = (_Float16)(-2.f * g1b);   \
        }                                                                      \
    } while (0)

    // Compute one half-stage (64 rows): both njs jointly, 4 MFMA chains.
#define COMPUTE_HS(buf, t)                                                     \
    do {                                                                       \
        const int r0_ = by * 1024 + (t) * 64;                                  \
        const _Float16* sb_ = &sB[(buf)][0];                                   \
        float16v A00 = (float16v)(0.f), A01 = (float16v)(0.f);                 \
        float16v A10 = (float16v)(0.f), A11 = (float16v)(0.f);                 \
        __builtin_amdgcn_s_setprio(1);                                         \
        _Pragma("unroll")                                                      \
        for (int s = 0; s < 16; ++s) {                                         \
            half8 bf0 = LDB(sb_, 0, s);                                        \
            half8 bf1 = LDB(sb_, 1, s);                                        \
            A00 = __builtin_amdgcn_mfma_f32_32x32x16_f16(afr[0][s], bf0, A00, 0, 0, 0); \
            A01 = __builtin_amdgcn_mfma_f32_32x32x16_f16(afr[1][s], bf0, A01, 0, 0, 0); \
            A10 = __builtin_amdgcn_mfma_f32_32x32x16_f16(afr[0][s], bf1, A10, 0, 0, 0); \
            A11 = __builtin_amdgcn_mfma_f32_32x32x16_f16(afr[1][s], bf1, A11, 0, 0, 0); \
        }                                                                      \
        A00 = __builtin_amdgcn_mfma_f32_32x32x16_f16(aext[0], bext, A00, 0, 0, 0); \
        A01 = __builtin_amdgcn_mfma_f32_32x32x16_f16(aext[1], bext, A01, 0, 0, 0); \
        A10 = __builtin_amdgcn_mfma_f32_32x32x16_f16(aext[0], bext, A10, 0, 0, 0); \
        A11 = __builtin_amdgcn_mfma_f32_32x32x16_f16(aext[1], bext, A11, 0, 0, 0); \
        __builtin_amdgcn_s_setprio(0);                                         \
        EPI(A00, A01, 0);                                                      \
        EPI(A10, A11, 1);                                                      \
    } while (0)

    // Prologue: stage half-stages 0 and 1.
    STAGE_HS(0, 0);
    STAGE_HS(1, 1);
    // t=0: queue = [8 loads-0][8 loads-1] -> vmcnt(8) retires loads-0.
    asm volatile("s_waitcnt vmcnt(8)" ::: "memory");
    __builtin_amdgcn_s_barrier();
    __builtin_amdgcn_sched_barrier(0);
    COMPUTE_HS(0, 0);
    __builtin_amdgcn_sched_barrier(0);
    __builtin_amdgcn_s_barrier();

    // Steady state t=1..14: queue at wait =
    // [8 loads-t][8 stores-(t-1)][8 loads-(t+1)] -> vmcnt(16).
#pragma unroll 1
    for (int t = 1; t < 15; ++t) {
        const int cur = t & 1;
        STAGE_HS(cur ^ 1, t + 1);
        asm volatile("s_waitcnt vmcnt(16)" ::: "memory");  // loads-t landed
        __builtin_amdgcn_s_barrier();
        __builtin_amdgcn_sched_barrier(0);
        COMPUTE_HS(cur, t);
        __builtin_amdgcn_sched_barrier(0);
        __builtin_amdgcn_s_barrier();
    }
    // Tail t=15: queue = [8 loads-15][8 stores-14] -> vmcnt(8).
    asm volatile("s_waitcnt vmcnt(8)" ::: "memory");
    __builtin_amdgcn_s_barrier();
    __builtin_amdgcn_sched_barrier(0);
    COMPUTE_HS(1, 15);

#undef STAGE_HS
#undef COMPUTE_HS
#undef LDB
#undef EPI
}

// ---------------------------------------------------------------------------
// Phase 2: wave-per-row (verified R4). LDS-transpose 64-row slab of smin_T,
// margin-filter granules, exact fp32 rescore ((hh+ee)-2*dot, lowest-index
// tie-break), gather zq, write out, bucketized loss.
// ---------------------------------------------------------------------------
__global__ __launch_bounds__(256, 2) void k_select(const float* __restrict__ h,
                                                   const float* __restrict__ cb,
                                                   const float* __restrict__ hh,
                                                   const float* __restrict__ ee,
                                                   const _Float16* __restrict__ smin,
                                                   float* __restrict__ out,
                                                   float* __restrict__ loss_part) {
    __shared__ _Float16 sS[64][512];  // [row][granule] = 64 KB
    const int t = threadIdx.x, lane = t & 63, w = t >> 6;
    const int r0 = blockIdx.x * 64;

    for (int gi = t; gi < NGRAN; gi += 256) {
        const _Float16* src = smin + (size_t)gi * M_TOT + r0;
#pragma unroll
        for (int c = 0; c < 8; ++c) {
            half8 v = *(const half8*)(src + c * 8);
#pragma unroll
            for (int j = 0; j < 8; ++j) sS[c * 8 + j][gi] = v[j];
        }
    }
    __syncthreads();

    float lossacc = 0.0f;
    for (int i = 0; i < 16; ++i) {
        const int row = r0 + w * 16 + i;
        float4v hv = *(const float4v*)&h[(size_t)row * DD + lane * 4];
        half8 sm = *(const half8*)&sS[w * 16 + i][lane * 8];
        float vmin = 1e30f;
        float sv[8];
#pragma unroll
        for (int j = 0; j < 8; ++j) {
            sv[j] = (float)sm[j];
            vmin = fminf(vmin, sv[j]);
        }
        float m2 = vmin;
#pragma unroll
        for (int o = 32; o; o >>= 1) m2 = fminf(m2, __shfl_xor(m2, o));
        const float thr = m2 + MARGIN;
        unsigned flags = 0;
#pragma unroll
        for (int j = 0; j < 8; ++j)
            if (sv[j] <= thr) flags |= (1u << j);

        unsigned long long act = __ballot(flags != 0);
        unsigned long long bestk = ~0ull;
        const float hhv = hh[row];
        while (act) {
            const int ln = __ffsll((long long)act) - 1;
            act &= act - 1;
            unsigned fl = (unsigned)__shfl((int)flags, ln);
            while (fl) {
                const int j = __ffs(fl) - 1;
                fl &= fl - 1;
                const int g = ln * 8 + j;
#pragma unroll
                for (int c = 0; c < 16; ++c) {
                    const int code = g * 16 + c;
                    float4v cv = *(const float4v*)&cb[(size_t)code * DD + lane * 4];
                    float s = hv.x * cv.x + hv.y * cv.y + hv.z * cv.z + hv.w * cv.w;
#pragma unroll
                    for (int o = 32; o; o >>= 1) s += __shfl_xor(s, o);
                    const float d = (hhv + ee[code]) - 2.0f * s;  // reference formula
                    const unsigned bts = __float_as_uint(d);
                    const unsigned mb =
                        bts ^ (unsigned)(((int)bts >> 31) | 0x80000000);
                    const unsigned long long key =
                        ((unsigned long long)mb << 32) | (unsigned)code;
                    if (key < bestk) bestk = key;
                }
            }
        }
        const unsigned best = (unsigned)(bestk & 0xffffffffull);
        float4v cv = *(const float4v*)&cb[(size_t)best * DD + lane * 4];
        *(float4v*)&out[(size_t)row * DD + lane * 4] = cv;
        const float dx = cv.x - hv.x, dy = cv.y - hv.y;
        const float dz = cv.z - hv.z, dw = cv.w - hv.w;
        lossacc += dx * dx + dy * dy + dz * dz + dw * dw;
    }
#pragma unroll
    for (int o = 32; o; o >>= 1) lossacc += __shfl_xor(lossacc, o);
    if (lane == 0)
        atomicAdd(&loss_part[(blockIdx.x * 4 + w) & (NBUCKET - 1)], lossacc);
}

__global__ __launch_bounds__(256) void k_final(const float* __restrict__ loss_part,
                                               float* __restrict__ out) {
    const int t = threadIdx.x;
    float s = loss_part[t];
#pragma unroll
    for (int off = 32; off; off >>= 1) s += __shfl_down(s, off);
    __shared__ float wsum[4];
    if ((t & 63) == 0) wsum[t >> 6] = s;
    __syncthreads();
    if (t == 0)
        out[0] = 1.25f * ((wsum[0] + wsum[1]) + (wsum[2] + wsum[3]))
                 / (float)(M_TOT * DD);  // BETA*mean + mean
}

// ---------------------------------------------------------------------------
extern "C" void kernel_launch(void* const* d_in, const int* in_sizes, int n_in,
                              void* d_out, int out_size, void* d_ws, size_t ws_size,
                              hipStream_t stream) {
    const float* x  = (const float*)d_in[0];
    const float* W  = (const float*)d_in[1];
    const float* b  = (const float*)d_in[2];
    const float* cb = (const float*)d_in[3];
    float* out = (float*)d_out;

    char* ws = (char*)d_ws;
    float* h        = (float*)(ws + OFF_H);
    _Float16* ht    = (_Float16*)(ws + OFF_HT);
    _Float16* cbt   = (_Float16*)(ws + OFF_CBT);
    _Float16* wt_hi = (_Float16*)(ws + OFF_WTH);
    _Float16* wt_lo = (_Float16*)(ws + OFF_WTL);
    float* hh       = (float*)(ws + OFF_HH);
    float* ee       = (float*)(ws + OFF_EE);
    _Float16* smin  = (_Float16*)(ws + OFF_SMIN);
    float* loss_part = (float*)(ws + OFF_LOSSP);

    hipLaunchKernelGGL(k_prep, dim3(512 + KCODES / 4), dim3(256), 0, stream,
                       W, cb, wt_hi, wt_lo, cbt, ee, loss_part);
    hipLaunchKernelGGL(k_gemm1, dim3(M_TOT / 64), dim3(256), 0, stream,
                       x, wt_hi, wt_lo, b, h, ht, hh);
    hipLaunchKernelGGL(k_dist, dim3(KCODES / 256, M_TOT / 1024), dim3(256),
                       0, stream, ht, cbt, ee, smin);
    hipLaunchKernelGGL(k_select, dim3(M_TOT / 64), dim3(256), 0, stream,
                       h, cb, hh, ee, smin, out, loss_part);
    hipLaunchKernelGGL(k_final, dim3(1), dim3(256), 0, stream,
                       loss_part, out + (size_t)M_TOT * DD);
}